// Round 10
// baseline (1280.603 us; speedup 1.0000x reference)
//
#include <hip/hip_runtime.h>
#include <stdint.h>

constexpr int SEQ    = 2048;
constexpr int DMODEL = 2048;
constexpr int NHEADS = 16;
constexpr int NKVH   = 4;
constexpr int HDIM   = 128;
constexpr int DFFN   = 8192;
constexpr int BATCH  = 2;
constexpr int MTOK   = BATCH * SEQ;   // 4096 tokens
constexpr int KKEEP  = DFFN / 2;      // 4096

typedef __bf16 bf16x8 __attribute__((ext_vector_type(8)));
typedef float  f32x4  __attribute__((ext_vector_type(4)));
typedef float  f32x16 __attribute__((ext_vector_type(16)));
typedef unsigned short u16;
typedef unsigned int   u32;

__device__ __forceinline__ u16 f2bu(float f) {  // f32 -> bf16 bits, RNE
  u32 x = __builtin_bit_cast(u32, f);
  return (u16)((x + 0x7FFFu + ((x >> 16) & 1u)) >> 16);
}
__device__ __forceinline__ float b2f(u16 u) {
  u32 v = ((u32)u) << 16;
  return __builtin_bit_cast(float, v);
}
__device__ __forceinline__ void gl_lds16(const void* g, void* l) {
  // 16B per lane; LDS dest = wave-uniform base + lane*16
  __builtin_amdgcn_global_load_lds((const __attribute__((address_space(1))) u32*)g,
                                   (__attribute__((address_space(3))) u32*)l, 16, 0, 0);
}

// ---------------- weight convert f32 -> bf16 ----------------
__global__ __launch_bounds__(256) void cvt_kernel(const float* __restrict__ in,
                                                  u16* __restrict__ out, int n) {
  int i = (blockIdx.x * 256 + threadIdx.x) * 4;
  if (i >= n) return;
  float4 v = *(const float4*)(in + i);
  uint2 pk;
  pk.x = (u32)f2bu(v.x) | ((u32)f2bu(v.y) << 16);
  pk.y = (u32)f2bu(v.z) | ((u32)f2bu(v.w) << 16);
  *(uint2*)(out + i) = pk;
}

// ---------------- reduce: out += p0 + p1 (split-K epilogue) ----------------
__global__ __launch_bounds__(256) void redadd_kernel(float* __restrict__ out,
                                                     const float* __restrict__ p0,
                                                     const float* __restrict__ p1) {
  int i = (blockIdx.x * 256 + threadIdx.x) * 4;
  float4 o = *(const float4*)(out + i);
  float4 a = *(const float4*)(p0 + i);
  float4 b = *(const float4*)(p1 + i);
  o.x += a.x + b.x; o.y += a.y + b.y; o.z += a.z + b.z; o.w += a.w + b.w;
  *(float4*)(out + i) = o;
}

// ---------------- RMSNorm: f32 row -> bf16 row ----------------
__global__ __launch_bounds__(256) void rmsnorm_kernel(const float* __restrict__ in,
                                                      const float* __restrict__ w,
                                                      u16* __restrict__ out) {
  const int tid = threadIdx.x;
  const size_t row = blockIdx.x;
  const float* x = in + row * DMODEL;
  float4 v0 = *(const float4*)(x + tid * 4);
  float4 v1 = *(const float4*)(x + 1024 + tid * 4);
  float s = v0.x*v0.x + v0.y*v0.y + v0.z*v0.z + v0.w*v0.w
          + v1.x*v1.x + v1.y*v1.y + v1.z*v1.z + v1.w*v1.w;
#pragma unroll
  for (int off = 1; off < 64; off <<= 1) s += __shfl_xor(s, off, 64);
  __shared__ float wsum[4];
  if ((tid & 63) == 0) wsum[tid >> 6] = s;
  __syncthreads();
  s = wsum[0] + wsum[1] + wsum[2] + wsum[3];
  const float rinv = rsqrtf(s * (1.0f / DMODEL) + 1e-6f);
  u16* o = out + row * DMODEL;
#pragma unroll
  for (int part = 0; part < 2; ++part) {
    int c = part * 1024 + tid * 4;
    float4 vv = (part == 0) ? v0 : v1;
    float4 wv = *(const float4*)(w + c);
    uint2 pk;
    pk.x = (u32)f2bu(vv.x * rinv * wv.x) | ((u32)f2bu(vv.y * rinv * wv.y) << 16);
    pk.y = (u32)f2bu(vv.z * rinv * wv.z) | ((u32)f2bu(vv.w * rinv * wv.w) << 16);
    *(uint2*)(o + c) = pk;
  }
}

// ---------------- 128x128 GEMM (min-2-phase), C = A @ B^T ------------------
// EPI: 0 = bf16 store, 1 = transposed V store, 2 = f32 + residual (res may
//      alias C), 3 = f32 silu
template <int EPI>
__global__ __launch_bounds__(256, 2)
void gemm_bt(const u16* __restrict__ A, const u16* __restrict__ B,
             void* __restrict__ C, const float* res,
             int M, int N, int K) {
  __shared__ u16 As[2][128 * 64];
  __shared__ u16 Bs[2][128 * 64];
  const int tid = threadIdx.x;
  const int wave = tid >> 6, lane = tid & 63;
  const int nwg = gridDim.x * gridDim.y;
  const int lin = blockIdx.y * gridDim.x + blockIdx.x;
  const int swz = (lin & 7) * (nwg >> 3) + (lin >> 3);
  const int m0 = (swz / gridDim.x) * 128, n0 = (swz % gridDim.x) * 128;
  const int r_in = lane >> 3, chk = lane & 7;   // staging: 8 rows x 8 chunks / KB
  const int fk = lane >> 4, fc = lane & 15;     // MFMA fragment indices
  const int wm = (wave >> 1) * 64, wn = (wave & 1) * 64;
  const int nt = K >> 6;
  f32x4 acc[4][4] = {};

  auto stage = [&](int buf, int t) {
    const int kt = t * 64;
#pragma unroll
    for (int i = 0; i < 4; ++i) {
      int row = wave * 32 + i * 8 + r_in;
      int gc = chk ^ (row & 7);   // pre-swizzled source, linear LDS dest
      gl_lds16(A + (size_t)(m0 + row) * K + kt + gc * 8, &As[buf][(wave * 32 + i * 8) * 64]);
    }
#pragma unroll
    for (int i = 0; i < 4; ++i) {
      int row = wave * 32 + i * 8 + r_in;
      int gc = chk ^ (row & 7);
      gl_lds16(B + (size_t)(n0 + row) * K + kt + gc * 8, &Bs[buf][(wave * 32 + i * 8) * 64]);
    }
  };

  stage(0, 0);
  asm volatile("s_waitcnt vmcnt(0)" ::: "memory");
  __builtin_amdgcn_s_barrier();

  for (int t = 0; t < nt; ++t) {
    if (t + 1 < nt) stage((t + 1) & 1, t + 1);   // issue-early: overlaps MFMA below
    const u16* Ab = As[t & 1];
    const u16* Bb = Bs[t & 1];
#pragma unroll
    for (int kk = 0; kk < 2; ++kk) {
      bf16x8 a[4], b[4];
#pragma unroll
      for (int i = 0; i < 4; ++i) {
        int row = wm + i * 16 + fc;
        int c = (kk * 4 + fk) ^ (row & 7);
        a[i] = *(const bf16x8*)(Ab + row * 64 + c * 8);
      }
#pragma unroll
      for (int j = 0; j < 4; ++j) {
        int row = wn + j * 16 + fc;
        int c = (kk * 4 + fk) ^ (row & 7);
        b[j] = *(const bf16x8*)(Bb + row * 64 + c * 8);
      }
#pragma unroll
      for (int i = 0; i < 4; ++i)
#pragma unroll
        for (int j = 0; j < 4; ++j)
          acc[i][j] = __builtin_amdgcn_mfma_f32_16x16x32_bf16(a[i], b[j], acc[i][j], 0, 0, 0);
    }
    asm volatile("s_waitcnt vmcnt(0)" ::: "memory");  // staged loads landed (late drain)
    __builtin_amdgcn_s_barrier();
  }

  const int rb = fk * 4;  // C/D: col = lane&15, row = (lane>>4)*4 + reg
#pragma unroll
  for (int i = 0; i < 4; ++i) {
#pragma unroll
    for (int j = 0; j < 4; ++j) {
      int row = m0 + wm + i * 16 + rb;
      int col = n0 + wn + j * 16 + fc;
      f32x4 v = acc[i][j];
      if constexpr (EPI == 0) {
        u16* o = (u16*)C;
#pragma unroll
        for (int r = 0; r < 4; ++r) o[(size_t)(row + r) * N + col] = f2bu(v[r]);
      } else if constexpr (EPI == 1) {
        // vt[b][kvh][d][s] ; row = token (4 consecutive s), col = kvh*128+d
        u16* o = (u16*)C;
        int bb = row >> 11, s = row & (SEQ - 1);
        int kvh = col >> 7, d = col & (HDIM - 1);
        size_t base = (((size_t)bb * NKVH + kvh) * HDIM + d) * SEQ + s;
        uint2 pk;
        pk.x = (u32)f2bu(v[0]) | ((u32)f2bu(v[1]) << 16);
        pk.y = (u32)f2bu(v[2]) | ((u32)f2bu(v[3]) << 16);
        *(uint2*)(o + base) = pk;
      } else if constexpr (EPI == 2) {
        float* o = (float*)C;
#pragma unroll
        for (int r = 0; r < 4; ++r) {
          size_t idx = (size_t)(row + r) * N + col;
          float rv = res[idx];
          o[idx] = v[r] + rv;
        }
      } else {  // EPI == 3 : silu
        float* o = (float*)C;
#pragma unroll
        for (int r = 0; r < 4; ++r) {
          float g = v[r];
          o[(size_t)(row + r) * N + col] = g / (1.0f + __expf(-g));
        }
      }
    }
  }
}

// ---------------- 256x256 GEMM, 8-phase counted-vmcnt schedule -------------
// Hoisted-read variant: each phase's a-frag reads (+ deferred b1 reads) are
// issued INSIDE the previous phase's MFMA window (after midbar's lgkm-drain,
// pinned by sched_barrier so they fly under the MFMAs). aX/aY double-buffer.
// vmcnt ledger identical to the proven round-8 schedule. Hazards: hoisted
// reads of phase p are drained by phase p's lgkmcnt(0), which precedes phase
// p's end-barrier, which precedes any wave's phase-p+1 stage issue.
template <int EPI>
__global__ __launch_bounds__(512, 2)
void gemm256(const u16* __restrict__ A, const u16* __restrict__ B,
             void* __restrict__ C, void* __restrict__ C2,
             int M, int N, int K, int lda) {
  __shared__ u16 As[2][2][128 * 64];
  __shared__ u16 Bs[2][2][128 * 64];
  const int tid = threadIdx.x;
  const int wave = tid >> 6, lane = tid & 63;
  const int nwg = gridDim.x * gridDim.y;
  const int lin = blockIdx.y * gridDim.x + blockIdx.x;
  const int swz = (lin & 7) * (nwg >> 3) + (lin >> 3);
  const int m0 = (swz / gridDim.x) * 256, n0 = (swz % gridDim.x) * 256;
  const int kh = blockIdx.z;
  A += (size_t)kh * K;
  B += (size_t)kh * K;
  const int wm = wave >> 2, wn = wave & 3;
  const int fk = lane >> 4, fc = lane & 15;
  const int nt = K >> 6, ni = nt >> 1;
  const int s_sub = lane >> 3;
  const int s_gc  = (lane & 7) ^ s_sub;   // pre-swizzled source chunk
  f32x4 acc[8][4] = {};
  bf16x8 b0[4], b1[4], aX[4], aY[4];

  auto sA = [&](int buf, int h, int t) {   // stage one A half-tile (2 loads)
    const u16* src = A + (size_t)(m0 + h * 128) * lda + t * 64;
    u16* dst = &As[buf][h][0];
#pragma unroll
    for (int I = 0; I < 2; ++I) {
      int row = I * 64 + wave * 8 + s_sub;
      gl_lds16(src + (size_t)row * lda + s_gc * 8, dst + (I * 512 + wave * 64) * 8);
    }
  };
  auto sB = [&](int buf, int h, int t) {
    const u16* src = B + (size_t)(n0 + h * 128) * lda + t * 64;
    u16* dst = &Bs[buf][h][0];
#pragma unroll
    for (int I = 0; I < 2; ++I) {
      int row = I * 64 + wave * 8 + s_sub;
      gl_lds16(src + (size_t)row * lda + s_gc * 8, dst + (I * 512 + wave * 64) * 8);
    }
  };
  auto rb0 = [&](const u16* Bh) {
#pragma unroll
    for (int n = 0; n < 4; ++n) {
      int row = (wn & 1) * 64 + n * 16 + fc;
      b0[n] = *(const bf16x8*)(Bh + row * 64 + ((fk) ^ (row & 7)) * 8);
    }
  };
  auto rb1 = [&](const u16* Bh) {
#pragma unroll
    for (int n = 0; n < 4; ++n) {
      int row = (wn & 1) * 64 + n * 16 + fc;
      b1[n] = *(const bf16x8*)(Bh + row * 64 + ((4 + fk) ^ (row & 7)) * 8);
    }
  };
  auto ra = [&](bf16x8* dst, const u16* Ah, int mh, int kk) {
#pragma unroll
    for (int m = 0; m < 4; ++m) {
      int row = mh * 64 + m * 16 + fc;
      dst[m] = *(const bf16x8*)(Ah + row * 64 + ((kk * 4 + fk) ^ (row & 7)) * 8);
    }
  };
  auto midbar = [&]() {
    __builtin_amdgcn_s_barrier();
    asm volatile("s_waitcnt lgkmcnt(0)" ::: "memory");
    __builtin_amdgcn_sched_barrier(0);
    __builtin_amdgcn_s_setprio(1);
  };
  auto endbar = [&]() {
    __builtin_amdgcn_s_setprio(0);
    __builtin_amdgcn_s_barrier();
  };
  auto mfma16 = [&](int mh, bf16x8* bb, bf16x8* aa) {
#pragma unroll
    for (int m = 0; m < 4; ++m)
#pragma unroll
      for (int n = 0; n < 4; ++n)
        acc[mh * 4 + m][n] =
            __builtin_amdgcn_mfma_f32_16x16x32_bf16(aa[m], bb[n], acc[mh * 4 + m][n], 0, 0, 0);
  };

  // prologue: u0 {B0,B1,A0,A1}, v0 {B0,B1}; retire u0, keep v0B in flight
  sB(0, 0, 0); sB(0, 1, 0);
  sA(0, 0, 0); sA(0, 1, 0);
  sB(1, 0, 1); sB(1, 1, 1);
  asm volatile("s_waitcnt vmcnt(4)" ::: "memory");
  __builtin_amdgcn_s_barrier();

  for (int i = 0; i < ni; ++i) {
    const int u = 2 * i, v = 2 * i + 1;
    const bool more = (i + 1 < ni);
    const u16* Au = &As[0][wm][0];
    const u16* Bu = &Bs[0][wn >> 1][0];
    const u16* Av = &As[1][wm][0];
    const u16* Bv = &Bs[1][wn >> 1][0];
    // ---- u window ----
    rb0(Bu); ra(aX, Au, 0, 0); sA(1, 0, v);            // ph1 entry (8 reads)
    midbar();
    ra(aY, Au, 1, 0); rb1(Bu);                         // hoisted under MFMA
    __builtin_amdgcn_sched_barrier(0);
    mfma16(0, b0, aX); endbar();
    sA(1, 1, v);                                       // ph2
    midbar();
    ra(aX, Au, 0, 1);
    __builtin_amdgcn_sched_barrier(0);
    mfma16(1, b0, aY); endbar();
    if (more) sB(0, 0, u + 2);                         // ph3
    midbar();
    ra(aY, Au, 1, 1);
    __builtin_amdgcn_sched_barrier(0);
    mfma16(0, b1, aX); endbar();
    if (more) sB(0, 1, u + 2);                         // ph4
    midbar();
    mfma16(1, b1, aY);
    __builtin_amdgcn_s_setprio(0);
    if (more) asm volatile("s_waitcnt vmcnt(4)" ::: "memory");
    else      asm volatile("s_waitcnt vmcnt(0)" ::: "memory");
    __builtin_amdgcn_s_barrier();
    // ---- v window ----
    rb0(Bv); ra(aX, Av, 0, 0); if (more) sA(0, 0, u + 2);  // ph5
    midbar();
    ra(aY, Av, 1, 0); rb1(Bv);
    __builtin_amdgcn_sched_barrier(0);
    mfma16(0, b0, aX); endbar();
    if (more) sA(0, 1, u + 2);                         // ph6
    midbar();
    ra(aX, Av, 0, 1);
    __builtin_amdgcn_sched_barrier(0);
    mfma16(1, b0, aY); endbar();
    if (more) sB(1, 0, v + 2);                         // ph7
    midbar();
    ra(aY, Av, 1, 1);
    __builtin_amdgcn_sched_barrier(0);
    mfma16(0, b1, aX); endbar();
    if (more) sB(1, 1, v + 2);                         // ph8
    midbar();
    mfma16(1, b1, aY);
    __builtin_amdgcn_s_setprio(0);
    if (more) {
      asm volatile("s_waitcnt vmcnt(4)" ::: "memory");
    }
    __builtin_amdgcn_s_barrier();
  }

  const int rbase = fk * 4;  // C/D: col = lane&15, row = (lane>>4)*4 + reg
#pragma unroll
  for (int m = 0; m < 8; ++m) {
#pragma unroll
    for (int n = 0; n < 4; ++n) {
      int row = m0 + wm * 128 + m * 16 + rbase;
      int col = n0 + wn * 64 + n * 16 + fc;
      f32x4 vv = acc[m][n];
      if constexpr (EPI == 0) {
        u16* o = (u16*)C;
#pragma unroll
        for (int r = 0; r < 4; ++r) o[(size_t)(row + r) * N + col] = f2bu(vv[r]);
      } else if constexpr (EPI == 3) {  // f32 silu
        float* o = (float*)C;
#pragma unroll
        for (int r = 0; r < 4; ++r) {
          float g = vv[r];
          o[(size_t)(row + r) * N + col] = g / (1.0f + __expf(-g));
        }
      } else {  // EPI == 4 : f32 partial store (split-K)
        float* o = (kh == 0) ? (float*)C : (float*)C2;
#pragma unroll
        for (int r = 0; r < 4; ++r) o[(size_t)(row + r) * N + col] = vv[r];
      }
    }
  }
}

// ---------------- flash attention (causal GQA, swapped-QK, 32x32 MFMA) -----
__global__ __launch_bounds__(256, 2)
void attn_kernel(const u16* __restrict__ Q, const u16* __restrict__ Kb,
                 const u16* __restrict__ Vt, u16* __restrict__ O) {
  __shared__ u16 Ksh[2 * 32 * 128];   // [buf][kv][d], chunk^(kv&15) swizzle
  __shared__ u16 Vsh[2 * 128 * 32];   // [buf][d][kv], chunk^((d>>1)&3) swizzle
  const int tid = threadIdx.x, wave = tid >> 6, lane = tid & 63;
  const int half = lane >> 5, l31 = lane & 31;
  // Remap: d and d+256 share (b,h) with complementary bx (pair work = 72
  // tiles, balances causal tail); d&7 pins one (b,kvh) per XCD for L2.
  const int d_lin = blockIdx.x + gridDim.x * (blockIdx.y + gridDim.y * blockIdx.z);
  const int x = d_lin & 255, hi = d_lin >> 8;
  const int e = (x & 7) * 32 + (x >> 3);
  const int q = e & 7, h = (e >> 3) & 15, b = e >> 7;
  const int bx = hi ? 15 - q : q;
  const int kvh = h >> 2;
  const int qw = bx * 128 + wave * 32;
  const float SC = 0.08838834764831845f;  // 1/sqrt(128)
  const int ntb = bx * 4 + 4;             // staged tiles per block
  const int nmy = bx * 4 + wave;          // last tile index this wave computes

  bf16x8 qf[8];
  {
    const u16* qp = Q + ((size_t)(b * SEQ + qw + l31)) * DMODEL + h * HDIM + half * 8;
#pragma unroll
    for (int s = 0; s < 8; ++s) qf[s] = *(const bf16x8*)(qp + s * 16);
  }
  f32x16 oacc[4] = {};
  float m_run = -1e30f, l_run = 0.0f;
  const size_t vbase = ((size_t)(b * NKVH + kvh)) * HDIM * SEQ;
  const u16* kbase = Kb + (size_t)b * SEQ * (NKVH * HDIM) + kvh * HDIM;

  auto stage = [&](int bi, int k0) {
    u16* Kd = Ksh + bi * 4096;
    u16* Vd = Vsh + bi * 4096;
#pragma unroll
    for (int ii = 0; ii < 2; ++ii) {
      int inst = wave * 2 + ii;
      {
        int row = inst * 4 + (lane >> 4);
        int c = (lane & 15) ^ (row & 15);
        gl_lds16(kbase + (size_t)(k0 + row) * (NKVH * HDIM) + c * 8, Kd + inst * 512);
      }
      {
        int row = inst * 16 + (lane >> 2);
        int c = (lane & 3) ^ ((row >> 1) & 3);
        gl_lds16(Vt + vbase + (size_t)row * SEQ + k0 + c * 8, Vd + inst * 512);
      }
    }
  };

  stage(0, 0);
  __syncthreads();

  for (int t = 0; t < ntb; ++t) {
    if (t + 1 < ntb) stage((t + 1) & 1, (t + 1) * 32);
    if (t <= nmy) {
      const u16* Kd = Ksh + (t & 1) * 4096;
      const u16* Vd = Vsh + (t & 1) * 4096;
      f32x16 st = {};
#pragma unroll
      for (int s = 0; s < 8; ++s) {
        int c = (half + 2 * s) ^ (l31 & 15);
        bf16x8 kf = *(const bf16x8*)(Kd + l31 * 128 + c * 8);
        st = __builtin_amdgcn_mfma_f32_32x32x16_bf16(kf, qf[s], st, 0, 0, 0);
      }
      const bool diag = (t * 32 == qw);
      float sv[16];
#pragma unroll
      for (int r = 0; r < 16; ++r) {
        float xx = st[r] * SC;
        if (diag) {
          int kvl = (r & 3) + 8 * (r >> 2) + 4 * half;
          if (kvl > l31) xx = -1e30f;
        }
        sv[r] = xx;
      }
      float mx = sv[0];
#pragma unroll
      for (int r = 1; r < 16; ++r) mx = fmaxf(mx, sv[r]);
      mx = fmaxf(mx, __shfl_xor(mx, 32, 64));
      if (__any(mx > m_run + 4.0f)) {   // defer-max (exact): rescale rarely
        float mnew = fmaxf(m_run, mx);
        float alpha = __expf(m_run - mnew);
        m_run = mnew;
        l_run *= alpha;
#pragma unroll
        for (int r = 0; r < 16; ++r) {
          float ar = __shfl(alpha, (r & 3) + 8 * (r >> 2) + 4 * half, 64);
#pragma unroll
          for (int dt = 0; dt < 4; ++dt) oacc[dt][r] *= ar;
        }
      }
      float p[16];
      float rs = 0.0f;
#pragma unroll
      for (int r = 0; r < 16; ++r) { p[r] = __expf(sv[r] - m_run); rs += p[r]; }
      rs += __shfl_xor(rs, 32, 64);
      l_run += rs;
      u32 c01 = (u32)f2bu(p[0])  | ((u32)f2bu(p[1])  << 16);
      u32 c23 = (u32)f2bu(p[2])  | ((u32)f2bu(p[3])  << 16);
      u32 c45 = (u32)f2bu(p[4])  | ((u32)f2bu(p[5])  << 16);
      u32 c67 = (u32)f2bu(p[6])  | ((u32)f2bu(p[7])  << 16);
      u32 c89 = (u32)f2bu(p[8])  | ((u32)f2bu(p[9])  << 16);
      u32 cAB = (u32)f2bu(p[10]) | ((u32)f2bu(p[11]) << 16);
      u32 cCD = (u32)f2bu(p[12]) | ((u32)f2bu(p[13]) << 16);
      u32 cEF = (u32)f2bu(p[14]) | ((u32)f2bu(p[15]) << 16);
      u32 paw[2][4];
      {
        u32 sA = __shfl_xor(c01, 32, 64), sB = __shfl_xor(c23, 32, 64);
        u32 sC = __shfl_xor(c45, 32, 64), sD = __shfl_xor(c67, 32, 64);
        paw[0][0] = half ? sC : c01;  paw[0][1] = half ? sD : c23;
        paw[0][2] = half ? c45 : sA;  paw[0][3] = half ? c67 : sB;
      }
      {
        u32 sA = __shfl_xor(c89, 32, 64), sB = __shfl_xor(cAB, 32, 64);
        u32 sC = __shfl_xor(cCD, 32, 64), sD = __shfl_xor(cEF, 32, 64);
        paw[1][0] = half ? sC : c89;  paw[1][1] = half ? sD : cAB;
        paw[1][2] = half ? cCD : sA;  paw[1][3] = half ? cEF : sB;
      }
#pragma unroll
      for (int ks = 0; ks < 2; ++ks) {
        bf16x8 paf = __builtin_bit_cast(bf16x8, *(uint4*)&paw[ks][0]);
#pragma unroll
        for (int dt = 0; dt < 4; ++dt) {
          int row = dt * 32 + l31;
          int c = (half + 2 * ks) ^ ((row >> 1) & 3);
          bf16x8 vf = *(const bf16x8*)(Vd + row * 32 + c * 8);
          oacc[dt] = __builtin_amdgcn_mfma_f32_32x32x16_bf16(paf, vf, oacc[dt], 0, 0, 0);
        }
      }
    }
    __syncthreads();
  }

  float rinv = 1.0f / l_run;
  u16* ob = O + ((size_t)(b * SEQ + qw)) * DMODEL + h * HDIM + l31;
#pragma unroll
  for (int r = 0; r < 16; ++r) {
    int qr = (r & 3) + 8 * (r >> 2) + 4 * half;
    float ir = __shfl(rinv, qr, 64);
#pragma unroll
    for (int dt = 0; dt < 4; ++dt)
      ob[(size_t)qr * DMODEL + dt * 32] = f2bu(oacc[dt][r] * ir);
  }
}

// ---------------- top-k (exact radix select) + gate*up, in-place over up ---
__global__ __launch_bounds__(256)
void topk_kernel(const float* __restrict__ gate, u16* __restrict__ upact) {
  __shared__ u32 sabs[DFFN];       // silu(gate) f32 bits
  __shared__ u32 hist[4][256];
  __shared__ u32 ss[257];
  __shared__ u32 sh_prefix, sh_rem;
  const int tid = threadIdx.x, wave = tid >> 6;
  const size_t row = blockIdx.x;
  const float* g = gate + row * DFFN;
  for (int it = 0; it < 4; ++it) {
    int e = it * 2048 + tid * 8;
    float4 a = *(const float4*)(g + e);
    float4 b = *(const float4*)(g + e + 4);
    sabs[e + 0] = __builtin_bit_cast(u32, a.x);
    sabs[e + 1] = __builtin_bit_cast(u32, a.y);
    sabs[e + 2] = __builtin_bit_cast(u32, a.z);
    sabs[e + 3] = __builtin_bit_cast(u32, a.w);
    sabs[e + 4] = __builtin_bit_cast(u32, b.x);
    sabs[e + 5] = __builtin_bit_cast(u32, b.y);
    sabs[e + 6] = __builtin_bit_cast(u32, b.z);
    sabs[e + 7] = __builtin_bit_cast(u32, b.w);
  }
  if (tid == 0) { sh_prefix = 0; sh_rem = KKEEP; }
  __syncthreads();
  for (int pass = 0; pass < 4; ++pass) {
    const int p = 24 - pass * 8;
    const u32 mask_hi = (pass == 0) ? 0u : (0xFFFFFFFFu << (p + 8));
    for (int i = tid; i < 1024; i += 256) ((u32*)hist)[i] = 0;
    __syncthreads();
    const u32 prefix = sh_prefix, rem = sh_rem;
    for (int it = 0; it < 4; ++it) {
      int e = it * 2048 + tid * 8;
#pragma unroll
      for (int j = 0; j < 8; ++j) {
        u32 mg = sabs[e + j] & 0x7FFFFFFFu;
        if ((mg & mask_hi) == (prefix & mask_hi))
          atomicAdd(&hist[wave][(mg >> p) & 0xFF], 1u);
      }
    }
    __syncthreads();
    ss[tid] = hist[0][tid] + hist[1][tid] + hist[2][tid] + hist[3][tid];
    if (tid == 0) ss[256] = 0;
    __syncthreads();
    for (int off = 1; off < 256; off <<= 1) {
      u32 v = (tid + off < 256) ? ss[tid + off] : 0u;
      __syncthreads();
      ss[tid] += v;
      __syncthreads();
    }
    if (ss[tid] >= rem && ss[tid + 1] < rem) {
      sh_prefix = prefix | ((u32)tid << p);
      sh_rem = rem - ss[tid + 1];
    }
    __syncthreads();
  }
  const u32 thr = sh_prefix;
  u16* ua = upact + row * DFFN;
  for (int it = 0; it < 4; ++it) {
    int e = it * 2048 + tid * 8;
    uint4 uv = *(const uint4*)(ua + e);
    const u16* up16 = (const u16*)&uv;
    u16 outp[8];
#pragma unroll
    for (int j = 0; j < 8; ++j) {
      u32 bits = sabs[e + j];
      u32 mg = bits & 0x7FFFFFFFu;
      float gg = __builtin_bit_cast(float, bits);
      float prod = (mg >= thr) ? gg * b2f(up16[j]) : 0.0f;
      outp[j] = f2bu(prod);
    }
    uint4 ov;
    ov.x = (u32)outp[0] | ((u32)outp[1] << 16);
    ov.y = (u32)outp[2] | ((u32)outp[3] << 16);
    ov.z = (u32)outp[4] | ((u32)outp[5] << 16);
    ov.w = (u32)outp[6] | ((u32)outp[7] << 16);
    *(uint4*)(ua + e) = ov;
  }
}

// ---------------- launcher ----------------
extern "C" void kernel_launch(void* const* d_in, const int* in_sizes, int n_in,
                              void* d_out, int out_size, void* d_ws, size_t ws_size,
                              hipStream_t stream) {
  const float* hidden = (const float*)d_in[0];
  const float* wq = (const float*)d_in[1];
  const float* wk = (const float*)d_in[2];
  const float* wv = (const float*)d_in[3];
  const float* wo = (const float*)d_in[4];
  const float* ln1 = (const float*)d_in[5];
  const float* ln2 = (const float*)d_in[6];
  const float* wg = (const float*)d_in[7];
  const float* wu = (const float*)d_in[8];
  const float* wd = (const float*)d_in[9];
  float* out = (float*)d_out;
  (void)in_sizes; (void)n_in; (void)out_size;

  // ---- workspace layout (lifetime-aliased, ~196 MB total) ----
  size_t off = 0;
  auto alloc = [&](size_t n) { char* r = (char*)d_ws + off; off += (n + 255) & ~(size_t)255; return r; };
  u16* wq_b = (u16*)alloc((size_t)DMODEL * DMODEL * 2);      // 8 MB
  u16* wk_b = (u16*)alloc((size_t)NKVH * HDIM * DMODEL * 2); // 2 MB
  u16* wv_b = (u16*)alloc((size_t)NKVH * HDIM * DMODEL * 2); // 2 MB
  u16* wo_b = (u16*)alloc((size_t)DMODEL * DMODEL * 2);      // 8 MB
  u16* wg_b = (u16*)alloc((size_t)DFFN * DMODEL * 2);        // 32 MB
  u16* tok  = (u16*)alloc((size_t)MTOK * DMODEL * 2);        // 16 MB: x -> o -> y
  u16* upb  = (u16*)alloc((size_t)MTOK * DFFN * 2);          // 64 MB
  char* S   = alloc((size_t)(MTOK / 2) * DFFN * 4);          // 64 MB shared region
  // S phase 1: qb(16) kb(4) vtb(4) wu_b(32)
  u16* qb   = (u16*)S;
  u16* kb   = (u16*)(S + (size_t)MTOK * DMODEL * 2);
  u16* vtb  = (u16*)(S + (size_t)MTOK * DMODEL * 2 + (size_t)MTOK * NKVH * HDIM * 2);
  u16* wu_b = (u16*)(S + (size_t)MTOK * DMODEL * 2 + 2 * (size_t)MTOK * NKVH * HDIM * 2);
  // S phase 2: gate half (f32, 2048 x 8192)
  float* gateh = (float*)S;
  // S phase 3: wd_b (32 MB) + split-K partial p1 (32 MB); p0 reuses wg_b slot
  u16* wd_b = (u16*)S;
  float* p1 = (float*)(S + (size_t)32 * 1024 * 1024);
  float* p0 = (float*)wg_b;   // wg_b dead after gate GEMMs
  const size_t needed = off;
  if (ws_size < needed) return;  // clean fast-fail (diagnostic) instead of OOB hang

  auto cvt = [&](const float* src, u16* dst, size_t n) {
    cvt_kernel<<<dim3((unsigned)(n / 1024)), 256, 0, stream>>>(src, dst, (int)n);
  };
  cvt(wq, wq_b, (size_t)DMODEL * DMODEL);
  cvt(wk, wk_b, (size_t)NKVH * HDIM * DMODEL);
  cvt(wv, wv_b, (size_t)NKVH * HDIM * DMODEL);
  cvt(wo, wo_b, (size_t)DMODEL * DMODEL);
  cvt(wg, wg_b, (size_t)DFFN * DMODEL);
  cvt(wu, wu_b, (size_t)DFFN * DMODEL);

  // x = rmsnorm(hidden, ln1)
  rmsnorm_kernel<<<MTOK, 256, 0, stream>>>(hidden, ln1, tok);

  gemm_bt<0><<<dim3(DMODEL / 128, MTOK / 128), 256, 0, stream>>>(
      tok, wq_b, qb, nullptr, MTOK, DMODEL, DMODEL);
  gemm_bt<0><<<dim3(NKVH * HDIM / 128, MTOK / 128), 256, 0, stream>>>(
      tok, wk_b, kb, nullptr, MTOK, NKVH * HDIM, DMODEL);
  gemm_bt<1><<<dim3(NKVH * HDIM / 128, MTOK / 128), 256, 0, stream>>>(
      tok, wv_b, vtb, nullptr, MTOK, NKVH * HDIM, DMODEL);

  // o -> tok (x dead)
  attn_kernel<<<dim3(SEQ / 128, NHEADS, BATCH), 256, 0, stream>>>(qb, kb, vtb, tok);

  // h = hidden + o @ wo^T   -> stored in d_out
  gemm_bt<2><<<dim3(DMODEL / 128, MTOK / 128), 256, 0, stream>>>(
      tok, wo_b, out, hidden, MTOK, DMODEL, DMODEL);

  // y = rmsnorm(h, ln2) -> tok (o dead)
  rmsnorm_kernel<<<MTOK, 256, 0, stream>>>(out, ln2, tok);

  // up = y @ wu^T (bf16) — 256^2 8-phase kernel (512 blocks)
  gemm256<0><<<dim3(DFFN / 256, MTOK / 256), 512, 0, stream>>>(
      tok, wu_b, upb, nullptr, MTOK, DFFN, DMODEL, DMODEL);

  // gate halves: silu(y @ wg^T) f32 (256 blocks each) -> topk into upb
  for (int half = 0; half < 2; ++half) {
    const u16* yh = tok + (size_t)half * (MTOK / 2) * DMODEL;
    u16* uph = upb + (size_t)half * (MTOK / 2) * DFFN;
    gemm256<3><<<dim3(DFFN / 256, (MTOK / 2) / 256), 512, 0, stream>>>(
        yh, wg_b, gateh, nullptr, MTOK / 2, DFFN, DMODEL, DMODEL);
    topk_kernel<<<MTOK / 2, 256, 0, stream>>>(gateh, uph);
  }

  // wd -> bf16 (into S low half; gate halves dead, wg_b dead -> p0)
  cvt(wd, wd_b, (size_t)DMODEL * DFFN);

  // down: split-K x2 over the 8-phase 256^2 kernel (256 blocks = full chip)
  gemm256<4><<<dim3(DMODEL / 256, MTOK / 256, 2), 512, 0, stream>>>(
      upb, wd_b, p0, p1, MTOK, DMODEL, DFFN / 2, DFFN);

  // out = h + p0 + p1
  redadd_kernel<<<(MTOK * DMODEL) / 1024, 256, 0, stream>>>(out, p0, p1);
}

// Round 11
// 1051.368 us; speedup vs baseline: 1.2180x; 1.2180x over previous
//
#include <hip/hip_runtime.h>
#include <stdint.h>

constexpr int SEQ    = 2048;
constexpr int DMODEL = 2048;
constexpr int NHEADS = 16;
constexpr int NKVH   = 4;
constexpr int HDIM   = 128;
constexpr int DFFN   = 8192;
constexpr int BATCH  = 2;
constexpr int MTOK   = BATCH * SEQ;   // 4096 tokens
constexpr int KKEEP  = DFFN / 2;      // 4096

typedef __bf16 bf16x8 __attribute__((ext_vector_type(8)));
typedef float  f32x4  __attribute__((ext_vector_type(4)));
typedef float  f32x16 __attribute__((ext_vector_type(16)));
typedef unsigned short u16;
typedef unsigned int   u32;

__device__ __forceinline__ u16 f2bu(float f) {  // f32 -> bf16 bits, RNE
  u32 x = __builtin_bit_cast(u32, f);
  return (u16)((x + 0x7FFFu + ((x >> 16) & 1u)) >> 16);
}
__device__ __forceinline__ float b2f(u16 u) {
  u32 v = ((u32)u) << 16;
  return __builtin_bit_cast(float, v);
}
__device__ __forceinline__ void gl_lds16(const void* g, void* l) {
  // 16B per lane; LDS dest = wave-uniform base + lane*16
  __builtin_amdgcn_global_load_lds((const __attribute__((address_space(1))) u32*)g,
                                   (__attribute__((address_space(3))) u32*)l, 16, 0, 0);
}

// ---------------- weight convert f32 -> bf16 ----------------
__global__ __launch_bounds__(256) void cvt_kernel(const float* __restrict__ in,
                                                  u16* __restrict__ out, int n) {
  int i = (blockIdx.x * 256 + threadIdx.x) * 4;
  if (i >= n) return;
  float4 v = *(const float4*)(in + i);
  uint2 pk;
  pk.x = (u32)f2bu(v.x) | ((u32)f2bu(v.y) << 16);
  pk.y = (u32)f2bu(v.z) | ((u32)f2bu(v.w) << 16);
  *(uint2*)(out + i) = pk;
}

// ---------------- reduce: out += p0 + p1 (split-K epilogue) ----------------
__global__ __launch_bounds__(256) void redadd_kernel(float* __restrict__ out,
                                                     const float* __restrict__ p0,
                                                     const float* __restrict__ p1) {
  int i = (blockIdx.x * 256 + threadIdx.x) * 4;
  float4 o = *(const float4*)(out + i);
  float4 a = *(const float4*)(p0 + i);
  float4 b = *(const float4*)(p1 + i);
  o.x += a.x + b.x; o.y += a.y + b.y; o.z += a.z + b.z; o.w += a.w + b.w;
  *(float4*)(out + i) = o;
}

// ---------------- RMSNorm: f32 row -> bf16 row ----------------
__global__ __launch_bounds__(256) void rmsnorm_kernel(const float* __restrict__ in,
                                                      const float* __restrict__ w,
                                                      u16* __restrict__ out) {
  const int tid = threadIdx.x;
  const size_t row = blockIdx.x;
  const float* x = in + row * DMODEL;
  float4 v0 = *(const float4*)(x + tid * 4);
  float4 v1 = *(const float4*)(x + 1024 + tid * 4);
  float s = v0.x*v0.x + v0.y*v0.y + v0.z*v0.z + v0.w*v0.w
          + v1.x*v1.x + v1.y*v1.y + v1.z*v1.z + v1.w*v1.w;
#pragma unroll
  for (int off = 1; off < 64; off <<= 1) s += __shfl_xor(s, off, 64);
  __shared__ float wsum[4];
  if ((tid & 63) == 0) wsum[tid >> 6] = s;
  __syncthreads();
  s = wsum[0] + wsum[1] + wsum[2] + wsum[3];
  const float rinv = rsqrtf(s * (1.0f / DMODEL) + 1e-6f);
  u16* o = out + row * DMODEL;
#pragma unroll
  for (int part = 0; part < 2; ++part) {
    int c = part * 1024 + tid * 4;
    float4 vv = (part == 0) ? v0 : v1;
    float4 wv = *(const float4*)(w + c);
    uint2 pk;
    pk.x = (u32)f2bu(vv.x * rinv * wv.x) | ((u32)f2bu(vv.y * rinv * wv.y) << 16);
    pk.y = (u32)f2bu(vv.z * rinv * wv.z) | ((u32)f2bu(vv.w * rinv * wv.w) << 16);
    *(uint2*)(o + c) = pk;
  }
}

// ---------------- 128x128 GEMM (min-2-phase), C = A @ B^T ------------------
// EPI: 0 = bf16 store, 1 = transposed V store, 2 = f32 + residual (res may
//      alias C), 3 = f32 silu
template <int EPI>
__global__ __launch_bounds__(256, 2)
void gemm_bt(const u16* __restrict__ A, const u16* __restrict__ B,
             void* __restrict__ C, const float* res,
             int M, int N, int K) {
  __shared__ u16 As[2][128 * 64];
  __shared__ u16 Bs[2][128 * 64];
  const int tid = threadIdx.x;
  const int wave = tid >> 6, lane = tid & 63;
  const int nwg = gridDim.x * gridDim.y;
  const int lin = blockIdx.y * gridDim.x + blockIdx.x;
  const int swz = (lin & 7) * (nwg >> 3) + (lin >> 3);
  const int m0 = (swz / gridDim.x) * 128, n0 = (swz % gridDim.x) * 128;
  const int r_in = lane >> 3, chk = lane & 7;   // staging: 8 rows x 8 chunks / KB
  const int fk = lane >> 4, fc = lane & 15;     // MFMA fragment indices
  const int wm = (wave >> 1) * 64, wn = (wave & 1) * 64;
  const int nt = K >> 6;
  f32x4 acc[4][4] = {};

  auto stage = [&](int buf, int t) {
    const int kt = t * 64;
#pragma unroll
    for (int i = 0; i < 4; ++i) {
      int row = wave * 32 + i * 8 + r_in;
      int gc = chk ^ (row & 7);   // pre-swizzled source, linear LDS dest
      gl_lds16(A + (size_t)(m0 + row) * K + kt + gc * 8, &As[buf][(wave * 32 + i * 8) * 64]);
    }
#pragma unroll
    for (int i = 0; i < 4; ++i) {
      int row = wave * 32 + i * 8 + r_in;
      int gc = chk ^ (row & 7);
      gl_lds16(B + (size_t)(n0 + row) * K + kt + gc * 8, &Bs[buf][(wave * 32 + i * 8) * 64]);
    }
  };

  stage(0, 0);
  asm volatile("s_waitcnt vmcnt(0)" ::: "memory");
  __builtin_amdgcn_s_barrier();

  for (int t = 0; t < nt; ++t) {
    if (t + 1 < nt) stage((t + 1) & 1, t + 1);   // issue-early: overlaps MFMA below
    const u16* Ab = As[t & 1];
    const u16* Bb = Bs[t & 1];
#pragma unroll
    for (int kk = 0; kk < 2; ++kk) {
      bf16x8 a[4], b[4];
#pragma unroll
      for (int i = 0; i < 4; ++i) {
        int row = wm + i * 16 + fc;
        int c = (kk * 4 + fk) ^ (row & 7);
        a[i] = *(const bf16x8*)(Ab + row * 64 + c * 8);
      }
#pragma unroll
      for (int j = 0; j < 4; ++j) {
        int row = wn + j * 16 + fc;
        int c = (kk * 4 + fk) ^ (row & 7);
        b[j] = *(const bf16x8*)(Bb + row * 64 + c * 8);
      }
#pragma unroll
      for (int i = 0; i < 4; ++i)
#pragma unroll
        for (int j = 0; j < 4; ++j)
          acc[i][j] = __builtin_amdgcn_mfma_f32_16x16x32_bf16(a[i], b[j], acc[i][j], 0, 0, 0);
    }
    asm volatile("s_waitcnt vmcnt(0)" ::: "memory");  // staged loads landed (late drain)
    __builtin_amdgcn_s_barrier();
  }

  const int rb = fk * 4;  // C/D: col = lane&15, row = (lane>>4)*4 + reg
#pragma unroll
  for (int i = 0; i < 4; ++i) {
#pragma unroll
    for (int j = 0; j < 4; ++j) {
      int row = m0 + wm + i * 16 + rb;
      int col = n0 + wn + j * 16 + fc;
      f32x4 v = acc[i][j];
      if constexpr (EPI == 0) {
        u16* o = (u16*)C;
#pragma unroll
        for (int r = 0; r < 4; ++r) o[(size_t)(row + r) * N + col] = f2bu(v[r]);
      } else if constexpr (EPI == 1) {
        // vt[b][kvh][d][s] ; row = token (4 consecutive s), col = kvh*128+d
        u16* o = (u16*)C;
        int bb = row >> 11, s = row & (SEQ - 1);
        int kvh = col >> 7, d = col & (HDIM - 1);
        size_t base = (((size_t)bb * NKVH + kvh) * HDIM + d) * SEQ + s;
        uint2 pk;
        pk.x = (u32)f2bu(v[0]) | ((u32)f2bu(v[1]) << 16);
        pk.y = (u32)f2bu(v[2]) | ((u32)f2bu(v[3]) << 16);
        *(uint2*)(o + base) = pk;
      } else if constexpr (EPI == 2) {
        float* o = (float*)C;
#pragma unroll
        for (int r = 0; r < 4; ++r) {
          size_t idx = (size_t)(row + r) * N + col;
          float rv = res[idx];
          o[idx] = v[r] + rv;
        }
      } else {  // EPI == 3 : silu
        float* o = (float*)C;
#pragma unroll
        for (int r = 0; r < 4; ++r) {
          float g = v[r];
          o[(size_t)(row + r) * N + col] = g / (1.0f + __expf(-g));
        }
      }
    }
  }
}

// ---------------- 256x256 GEMM, 8-phase counted-vmcnt schedule -------------
// Early-A-read ledger: all 4 a-fragment sets of a K-tile are read at the
// window's first two phase entries (a00/a10 @ ph1, a01/a11 @ ph2), so the
// A LDS buffer frees at ph2 and stage slots move later:
//  ph1: A1(v)  ph2: B0(u+2)  ph3: B1(u+2)  ph4: A0(u+2)
//  ph5: A1(u+2)  ph6: B0(v+2)  ph7: B1(v+2)  ph8: A0(v+2)
// Every staged half-tile now has >=4 phases of flight before its vmcnt.
// Steady state: outstanding 14 at ph4/ph8 ends; retire 8 -> vmcnt(6).
// Last iter: ph4 -> vmcnt(0) (A1(v) is newest outstanding), ph8 -> skip.
// WAR: As[buf] readers drain at ph2/ph6 midbar lgkm0, >=1 barrier before the
// overwriting stage issues; Bs at ph1/ph5. Skeleton/phase structure = proven
// round-8 form (no intra-phase pins beyond the standard midbar pair).
template <int EPI>
__global__ __launch_bounds__(512, 2)
void gemm256(const u16* __restrict__ A, const u16* __restrict__ B,
             void* __restrict__ C, void* __restrict__ C2,
             int M, int N, int K, int lda) {
  __shared__ u16 As[2][2][128 * 64];
  __shared__ u16 Bs[2][2][128 * 64];
  const int tid = threadIdx.x;
  const int wave = tid >> 6, lane = tid & 63;
  const int nwg = gridDim.x * gridDim.y;
  const int lin = blockIdx.y * gridDim.x + blockIdx.x;
  const int swz = (lin & 7) * (nwg >> 3) + (lin >> 3);
  const int m0 = (swz / gridDim.x) * 256, n0 = (swz % gridDim.x) * 256;
  const int kh = blockIdx.z;
  A += (size_t)kh * K;
  B += (size_t)kh * K;
  const int wm = wave >> 2, wn = wave & 3;
  const int fk = lane >> 4, fc = lane & 15;
  const int nt = K >> 6, ni = nt >> 1;
  const int s_sub = lane >> 3;
  const int s_gc  = (lane & 7) ^ s_sub;   // pre-swizzled source chunk
  f32x4 acc[8][4] = {};
  bf16x8 b0[4], b1[4], a00[4], a10[4], a01[4], a11[4];

  auto sA = [&](int buf, int h, int t) {   // stage one A half-tile (2 loads)
    const u16* src = A + (size_t)(m0 + h * 128) * lda + t * 64;
    u16* dst = &As[buf][h][0];
#pragma unroll
    for (int I = 0; I < 2; ++I) {
      int row = I * 64 + wave * 8 + s_sub;
      gl_lds16(src + (size_t)row * lda + s_gc * 8, dst + (I * 512 + wave * 64) * 8);
    }
  };
  auto sB = [&](int buf, int h, int t) {
    const u16* src = B + (size_t)(n0 + h * 128) * lda + t * 64;
    u16* dst = &Bs[buf][h][0];
#pragma unroll
    for (int I = 0; I < 2; ++I) {
      int row = I * 64 + wave * 8 + s_sub;
      gl_lds16(src + (size_t)row * lda + s_gc * 8, dst + (I * 512 + wave * 64) * 8);
    }
  };
  auto rb0 = [&](const u16* Bh) {
#pragma unroll
    for (int n = 0; n < 4; ++n) {
      int row = (wn & 1) * 64 + n * 16 + fc;
      b0[n] = *(const bf16x8*)(Bh + row * 64 + ((fk) ^ (row & 7)) * 8);
    }
  };
  auto rb1 = [&](const u16* Bh) {
#pragma unroll
    for (int n = 0; n < 4; ++n) {
      int row = (wn & 1) * 64 + n * 16 + fc;
      b1[n] = *(const bf16x8*)(Bh + row * 64 + ((4 + fk) ^ (row & 7)) * 8);
    }
  };
  auto ra = [&](bf16x8* dst, const u16* Ah, int mh, int kk) {
#pragma unroll
    for (int m = 0; m < 4; ++m) {
      int row = mh * 64 + m * 16 + fc;
      dst[m] = *(const bf16x8*)(Ah + row * 64 + ((kk * 4 + fk) ^ (row & 7)) * 8);
    }
  };
  auto midbar = [&]() {
    __builtin_amdgcn_s_barrier();
    asm volatile("s_waitcnt lgkmcnt(0)" ::: "memory");
    __builtin_amdgcn_sched_barrier(0);
    __builtin_amdgcn_s_setprio(1);
  };
  auto endbar = [&]() {
    __builtin_amdgcn_s_setprio(0);
    __builtin_amdgcn_s_barrier();
  };
  auto mfma16 = [&](int mh, bf16x8* bb, bf16x8* aa) {
#pragma unroll
    for (int m = 0; m < 4; ++m)
#pragma unroll
      for (int n = 0; n < 4; ++n)
        acc[mh * 4 + m][n] =
            __builtin_amdgcn_mfma_f32_16x16x32_bf16(aa[m], bb[n], acc[mh * 4 + m][n], 0, 0, 0);
  };

  // prologue: u0 {B0,B1,A0,A1} + v0 {B0,B1,A0}; retire u0, keep v0 (6) in flight
  sB(0, 0, 0); sB(0, 1, 0);
  sA(0, 0, 0); sA(0, 1, 0);
  sB(1, 0, 1); sB(1, 1, 1);
  sA(1, 0, 1);
  asm volatile("s_waitcnt vmcnt(6)" ::: "memory");
  __builtin_amdgcn_s_barrier();

  for (int i = 0; i < ni; ++i) {
    const int u = 2 * i, v = 2 * i + 1;
    const bool more = (i + 1 < ni);
    const u16* Au = &As[0][wm][0];
    const u16* Bu = &Bs[0][wn >> 1][0];
    const u16* Av = &As[1][wm][0];
    const u16* Bv = &Bs[1][wn >> 1][0];
    // ---- u window ----
    rb0(Bu); rb1(Bu); ra(a00, Au, 0, 0); ra(a10, Au, 1, 0);   // ph1: 16 reads
    sA(1, 1, v);
    midbar(); mfma16(0, b0, a00); endbar();
    ra(a01, Au, 0, 1); ra(a11, Au, 1, 1);                     // ph2: 8 reads
    if (more) sB(0, 0, u + 2);
    midbar(); mfma16(1, b0, a10); endbar();
    if (more) sB(0, 1, u + 2);                                // ph3
    midbar(); mfma16(0, b1, a01); endbar();
    if (more) sA(0, 0, u + 2);                                // ph4
    midbar(); mfma16(1, b1, a11);
    __builtin_amdgcn_s_setprio(0);
    if (more) asm volatile("s_waitcnt vmcnt(6)" ::: "memory");
    else      asm volatile("s_waitcnt vmcnt(0)" ::: "memory");
    __builtin_amdgcn_s_barrier();
    // ---- v window ----
    rb0(Bv); rb1(Bv); ra(a00, Av, 0, 0); ra(a10, Av, 1, 0);   // ph5: 16 reads
    if (more) sA(0, 1, u + 2);
    midbar(); mfma16(0, b0, a00); endbar();
    ra(a01, Av, 0, 1); ra(a11, Av, 1, 1);                     // ph6: 8 reads
    if (more) sB(1, 0, v + 2);
    midbar(); mfma16(1, b0, a10); endbar();
    if (more) sB(1, 1, v + 2);                                // ph7
    midbar(); mfma16(0, b1, a01); endbar();
    if (more) sA(1, 0, v + 2);                                // ph8
    midbar(); mfma16(1, b1, a11);
    __builtin_amdgcn_s_setprio(0);
    if (more) {
      asm volatile("s_waitcnt vmcnt(6)" ::: "memory");
    }
    __builtin_amdgcn_s_barrier();
  }

  const int rbase = fk * 4;  // C/D: col = lane&15, row = (lane>>4)*4 + reg
#pragma unroll
  for (int m = 0; m < 8; ++m) {
#pragma unroll
    for (int n = 0; n < 4; ++n) {
      int row = m0 + wm * 128 + m * 16 + rbase;
      int col = n0 + wn * 64 + n * 16 + fc;
      f32x4 vv = acc[m][n];
      if constexpr (EPI == 0) {
        u16* o = (u16*)C;
#pragma unroll
        for (int r = 0; r < 4; ++r) o[(size_t)(row + r) * N + col] = f2bu(vv[r]);
      } else if constexpr (EPI == 3) {  // f32 silu
        float* o = (float*)C;
#pragma unroll
        for (int r = 0; r < 4; ++r) {
          float g = vv[r];
          o[(size_t)(row + r) * N + col] = g / (1.0f + __expf(-g));
        }
      } else {  // EPI == 4 : f32 partial store (split-K)
        float* o = (kh == 0) ? (float*)C : (float*)C2;
#pragma unroll
        for (int r = 0; r < 4; ++r) o[(size_t)(row + r) * N + col] = vv[r];
      }
    }
  }
}

// ---------------- flash attention (causal GQA, swapped-QK, 32x32 MFMA) -----
__global__ __launch_bounds__(256, 2)
void attn_kernel(const u16* __restrict__ Q, const u16* __restrict__ Kb,
                 const u16* __restrict__ Vt, u16* __restrict__ O) {
  __shared__ u16 Ksh[2 * 32 * 128];   // [buf][kv][d], chunk^(kv&15) swizzle
  __shared__ u16 Vsh[2 * 128 * 32];   // [buf][d][kv], chunk^((d>>1)&3) swizzle
  const int tid = threadIdx.x, wave = tid >> 6, lane = tid & 63;
  const int half = lane >> 5, l31 = lane & 31;
  // Remap: d and d+256 share (b,h) with complementary bx (pair work = 72
  // tiles, balances causal tail); d&7 pins one (b,kvh) per XCD for L2.
  const int d_lin = blockIdx.x + gridDim.x * (blockIdx.y + gridDim.y * blockIdx.z);
  const int x = d_lin & 255, hi = d_lin >> 8;
  const int e = (x & 7) * 32 + (x >> 3);
  const int q = e & 7, h = (e >> 3) & 15, b = e >> 7;
  const int bx = hi ? 15 - q : q;
  const int kvh = h >> 2;
  const int qw = bx * 128 + wave * 32;
  const float SC = 0.08838834764831845f;  // 1/sqrt(128)
  const int ntb = bx * 4 + 4;             // staged tiles per block
  const int nmy = bx * 4 + wave;          // last tile index this wave computes

  bf16x8 qf[8];
  {
    const u16* qp = Q + ((size_t)(b * SEQ + qw + l31)) * DMODEL + h * HDIM + half * 8;
#pragma unroll
    for (int s = 0; s < 8; ++s) qf[s] = *(const bf16x8*)(qp + s * 16);
  }
  f32x16 oacc[4] = {};
  float m_run = -1e30f, l_run = 0.0f;
  const size_t vbase = ((size_t)(b * NKVH + kvh)) * HDIM * SEQ;
  const u16* kbase = Kb + (size_t)b * SEQ * (NKVH * HDIM) + kvh * HDIM;

  auto stage = [&](int bi, int k0) {
    u16* Kd = Ksh + bi * 4096;
    u16* Vd = Vsh + bi * 4096;
#pragma unroll
    for (int ii = 0; ii < 2; ++ii) {
      int inst = wave * 2 + ii;
      {
        int row = inst * 4 + (lane >> 4);
        int c = (lane & 15) ^ (row & 15);
        gl_lds16(kbase + (size_t)(k0 + row) * (NKVH * HDIM) + c * 8, Kd + inst * 512);
      }
      {
        int row = inst * 16 + (lane >> 2);
        int c = (lane & 3) ^ ((row >> 1) & 3);
        gl_lds16(Vt + vbase + (size_t)row * SEQ + k0 + c * 8, Vd + inst * 512);
      }
    }
  };

  stage(0, 0);
  __syncthreads();

  for (int t = 0; t < ntb; ++t) {
    if (t + 1 < ntb) stage((t + 1) & 1, (t + 1) * 32);
    if (t <= nmy) {
      const u16* Kd = Ksh + (t & 1) * 4096;
      const u16* Vd = Vsh + (t & 1) * 4096;
      f32x16 st = {};
#pragma unroll
      for (int s = 0; s < 8; ++s) {
        int c = (half + 2 * s) ^ (l31 & 15);
        bf16x8 kf = *(const bf16x8*)(Kd + l31 * 128 + c * 8);
        st = __builtin_amdgcn_mfma_f32_32x32x16_bf16(kf, qf[s], st, 0, 0, 0);
      }
      const bool diag = (t * 32 == qw);
      float sv[16];
#pragma unroll
      for (int r = 0; r < 16; ++r) {
        float xx = st[r] * SC;
        if (diag) {
          int kvl = (r & 3) + 8 * (r >> 2) + 4 * half;
          if (kvl > l31) xx = -1e30f;
        }
        sv[r] = xx;
      }
      float mx = sv[0];
#pragma unroll
      for (int r = 1; r < 16; ++r) mx = fmaxf(mx, sv[r]);
      mx = fmaxf(mx, __shfl_xor(mx, 32, 64));
      if (__any(mx > m_run + 4.0f)) {   // defer-max (exact): rescale rarely
        float mnew = fmaxf(m_run, mx);
        float alpha = __expf(m_run - mnew);
        m_run = mnew;
        l_run *= alpha;
#pragma unroll
        for (int r = 0; r < 16; ++r) {
          float ar = __shfl(alpha, (r & 3) + 8 * (r >> 2) + 4 * half, 64);
#pragma unroll
          for (int dt = 0; dt < 4; ++dt) oacc[dt][r] *= ar;
        }
      }
      float p[16];
      float rs = 0.0f;
#pragma unroll
      for (int r = 0; r < 16; ++r) { p[r] = __expf(sv[r] - m_run); rs += p[r]; }
      rs += __shfl_xor(rs, 32, 64);
      l_run += rs;
      u32 c01 = (u32)f2bu(p[0])  | ((u32)f2bu(p[1])  << 16);
      u32 c23 = (u32)f2bu(p[2])  | ((u32)f2bu(p[3])  << 16);
      u32 c45 = (u32)f2bu(p[4])  | ((u32)f2bu(p[5])  << 16);
      u32 c67 = (u32)f2bu(p[6])  | ((u32)f2bu(p[7])  << 16);
      u32 c89 = (u32)f2bu(p[8])  | ((u32)f2bu(p[9])  << 16);
      u32 cAB = (u32)f2bu(p[10]) | ((u32)f2bu(p[11]) << 16);
      u32 cCD = (u32)f2bu(p[12]) | ((u32)f2bu(p[13]) << 16);
      u32 cEF = (u32)f2bu(p[14]) | ((u32)f2bu(p[15]) << 16);
      u32 paw[2][4];
      {
        u32 sA = __shfl_xor(c01, 32, 64), sB = __shfl_xor(c23, 32, 64);
        u32 sC = __shfl_xor(c45, 32, 64), sD = __shfl_xor(c67, 32, 64);
        paw[0][0] = half ? sC : c01;  paw[0][1] = half ? sD : c23;
        paw[0][2] = half ? c45 : sA;  paw[0][3] = half ? c67 : sB;
      }
      {
        u32 sA = __shfl_xor(c89, 32, 64), sB = __shfl_xor(cAB, 32, 64);
        u32 sC = __shfl_xor(cCD, 32, 64), sD = __shfl_xor(cEF, 32, 64);
        paw[1][0] = half ? sC : c89;  paw[1][1] = half ? sD : cAB;
        paw[1][2] = half ? cCD : sA;  paw[1][3] = half ? cEF : sB;
      }
#pragma unroll
      for (int ks = 0; ks < 2; ++ks) {
        bf16x8 paf = __builtin_bit_cast(bf16x8, *(uint4*)&paw[ks][0]);
#pragma unroll
        for (int dt = 0; dt < 4; ++dt) {
          int row = dt * 32 + l31;
          int c = (half + 2 * ks) ^ ((row >> 1) & 3);
          bf16x8 vf = *(const bf16x8*)(Vd + row * 32 + c * 8);
          oacc[dt] = __builtin_amdgcn_mfma_f32_32x32x16_bf16(paf, vf, oacc[dt], 0, 0, 0);
        }
      }
    }
    __syncthreads();
  }

  float rinv = 1.0f / l_run;
  u16* ob = O + ((size_t)(b * SEQ + qw)) * DMODEL + h * HDIM + l31;
#pragma unroll
  for (int r = 0; r < 16; ++r) {
    int qr = (r & 3) + 8 * (r >> 2) + 4 * half;
    float ir = __shfl(rinv, qr, 64);
#pragma unroll
    for (int dt = 0; dt < 4; ++dt)
      ob[(size_t)qr * DMODEL + dt * 32] = f2bu(oacc[dt][r] * ir);
  }
}

// ---------------- top-k (exact radix select) + gate*up, in-place over up ---
__global__ __launch_bounds__(256)
void topk_kernel(const float* __restrict__ gate, u16* __restrict__ upact) {
  __shared__ u32 sabs[DFFN];       // silu(gate) f32 bits
  __shared__ u32 hist[4][256];
  __shared__ u32 ss[257];
  __shared__ u32 sh_prefix, sh_rem;
  const int tid = threadIdx.x, wave = tid >> 6;
  const size_t row = blockIdx.x;
  const float* g = gate + row * DFFN;
  for (int it = 0; it < 4; ++it) {
    int e = it * 2048 + tid * 8;
    float4 a = *(const float4*)(g + e);
    float4 b = *(const float4*)(g + e + 4);
    sabs[e + 0] = __builtin_bit_cast(u32, a.x);
    sabs[e + 1] = __builtin_bit_cast(u32, a.y);
    sabs[e + 2] = __builtin_bit_cast(u32, a.z);
    sabs[e + 3] = __builtin_bit_cast(u32, a.w);
    sabs[e + 4] = __builtin_bit_cast(u32, b.x);
    sabs[e + 5] = __builtin_bit_cast(u32, b.y);
    sabs[e + 6] = __builtin_bit_cast(u32, b.z);
    sabs[e + 7] = __builtin_bit_cast(u32, b.w);
  }
  if (tid == 0) { sh_prefix = 0; sh_rem = KKEEP; }
  __syncthreads();
  for (int pass = 0; pass < 4; ++pass) {
    const int p = 24 - pass * 8;
    const u32 mask_hi = (pass == 0) ? 0u : (0xFFFFFFFFu << (p + 8));
    for (int i = tid; i < 1024; i += 256) ((u32*)hist)[i] = 0;
    __syncthreads();
    const u32 prefix = sh_prefix, rem = sh_rem;
    for (int it = 0; it < 4; ++it) {
      int e = it * 2048 + tid * 8;
#pragma unroll
      for (int j = 0; j < 8; ++j) {
        u32 mg = sabs[e + j] & 0x7FFFFFFFu;
        if ((mg & mask_hi) == (prefix & mask_hi))
          atomicAdd(&hist[wave][(mg >> p) & 0xFF], 1u);
      }
    }
    __syncthreads();
    ss[tid] = hist[0][tid] + hist[1][tid] + hist[2][tid] + hist[3][tid];
    if (tid == 0) ss[256] = 0;
    __syncthreads();
    for (int off = 1; off < 256; off <<= 1) {
      u32 v = (tid + off < 256) ? ss[tid + off] : 0u;
      __syncthreads();
      ss[tid] += v;
      __syncthreads();
    }
    if (ss[tid] >= rem && ss[tid + 1] < rem) {
      sh_prefix = prefix | ((u32)tid << p);
      sh_rem = rem - ss[tid + 1];
    }
    __syncthreads();
  }
  const u32 thr = sh_prefix;
  u16* ua = upact + row * DFFN;
  for (int it = 0; it < 4; ++it) {
    int e = it * 2048 + tid * 8;
    uint4 uv = *(const uint4*)(ua + e);
    const u16* up16 = (const u16*)&uv;
    u16 outp[8];
#pragma unroll
    for (int j = 0; j < 8; ++j) {
      u32 bits = sabs[e + j];
      u32 mg = bits & 0x7FFFFFFFu;
      float gg = __builtin_bit_cast(float, bits);
      float prod = (mg >= thr) ? gg * b2f(up16[j]) : 0.0f;
      outp[j] = f2bu(prod);
    }
    uint4 ov;
    ov.x = (u32)outp[0] | ((u32)outp[1] << 16);
    ov.y = (u32)outp[2] | ((u32)outp[3] << 16);
    ov.z = (u32)outp[4] | ((u32)outp[5] << 16);
    ov.w = (u32)outp[6] | ((u32)outp[7] << 16);
    *(uint4*)(ua + e) = ov;
  }
}

// ---------------- launcher ----------------
extern "C" void kernel_launch(void* const* d_in, const int* in_sizes, int n_in,
                              void* d_out, int out_size, void* d_ws, size_t ws_size,
                              hipStream_t stream) {
  const float* hidden = (const float*)d_in[0];
  const float* wq = (const float*)d_in[1];
  const float* wk = (const float*)d_in[2];
  const float* wv = (const float*)d_in[3];
  const float* wo = (const float*)d_in[4];
  const float* ln1 = (const float*)d_in[5];
  const float* ln2 = (const float*)d_in[6];
  const float* wg = (const float*)d_in[7];
  const float* wu = (const float*)d_in[8];
  const float* wd = (const float*)d_in[9];
  float* out = (float*)d_out;
  (void)in_sizes; (void)n_in; (void)out_size;

  // ---- workspace layout (lifetime-aliased, ~196 MB total) ----
  size_t off = 0;
  auto alloc = [&](size_t n) { char* r = (char*)d_ws + off; off += (n + 255) & ~(size_t)255; return r; };
  u16* wq_b = (u16*)alloc((size_t)DMODEL * DMODEL * 2);      // 8 MB
  u16* wk_b = (u16*)alloc((size_t)NKVH * HDIM * DMODEL * 2); // 2 MB
  u16* wv_b = (u16*)alloc((size_t)NKVH * HDIM * DMODEL * 2); // 2 MB
  u16* wo_b = (u16*)alloc((size_t)DMODEL * DMODEL * 2);      // 8 MB
  u16* wg_b = (u16*)alloc((size_t)DFFN * DMODEL * 2);        // 32 MB
  u16* tok  = (u16*)alloc((size_t)MTOK * DMODEL * 2);        // 16 MB: x -> o -> y
  u16* upb  = (u16*)alloc((size_t)MTOK * DFFN * 2);          // 64 MB
  char* S   = alloc((size_t)(MTOK / 2) * DFFN * 4);          // 64 MB shared region
  // S phase 1: qb(16) kb(4) vtb(4) wu_b(32)
  u16* qb   = (u16*)S;
  u16* kb   = (u16*)(S + (size_t)MTOK * DMODEL * 2);
  u16* vtb  = (u16*)(S + (size_t)MTOK * DMODEL * 2 + (size_t)MTOK * NKVH * HDIM * 2);
  u16* wu_b = (u16*)(S + (size_t)MTOK * DMODEL * 2 + 2 * (size_t)MTOK * NKVH * HDIM * 2);
  // S phase 2: gate half (f32, 2048 x 8192)
  float* gateh = (float*)S;
  // S phase 3: wd_b (32 MB) + split-K partial p1 (32 MB); p0 reuses wg_b slot
  u16* wd_b = (u16*)S;
  float* p1 = (float*)(S + (size_t)32 * 1024 * 1024);
  float* p0 = (float*)wg_b;   // wg_b dead after gate GEMMs
  const size_t needed = off;
  if (ws_size < needed) return;  // clean fast-fail (diagnostic) instead of OOB hang

  auto cvt = [&](const float* src, u16* dst, size_t n) {
    cvt_kernel<<<dim3((unsigned)(n / 1024)), 256, 0, stream>>>(src, dst, (int)n);
  };
  cvt(wq, wq_b, (size_t)DMODEL * DMODEL);
  cvt(wk, wk_b, (size_t)NKVH * HDIM * DMODEL);
  cvt(wv, wv_b, (size_t)NKVH * HDIM * DMODEL);
  cvt(wo, wo_b, (size_t)DMODEL * DMODEL);
  cvt(wg, wg_b, (size_t)DFFN * DMODEL);
  cvt(wu, wu_b, (size_t)DFFN * DMODEL);

  // x = rmsnorm(hidden, ln1)
  rmsnorm_kernel<<<MTOK, 256, 0, stream>>>(hidden, ln1, tok);

  gemm_bt<0><<<dim3(DMODEL / 128, MTOK / 128), 256, 0, stream>>>(
      tok, wq_b, qb, nullptr, MTOK, DMODEL, DMODEL);
  gemm_bt<0><<<dim3(NKVH * HDIM / 128, MTOK / 128), 256, 0, stream>>>(
      tok, wk_b, kb, nullptr, MTOK, NKVH * HDIM, DMODEL);
  gemm_bt<1><<<dim3(NKVH * HDIM / 128, MTOK / 128), 256, 0, stream>>>(
      tok, wv_b, vtb, nullptr, MTOK, NKVH * HDIM, DMODEL);

  // o -> tok (x dead)
  attn_kernel<<<dim3(SEQ / 128, NHEADS, BATCH), 256, 0, stream>>>(qb, kb, vtb, tok);

  // h = hidden + o @ wo^T   -> stored in d_out
  gemm_bt<2><<<dim3(DMODEL / 128, MTOK / 128), 256, 0, stream>>>(
      tok, wo_b, out, hidden, MTOK, DMODEL, DMODEL);

  // y = rmsnorm(h, ln2) -> tok (o dead)
  rmsnorm_kernel<<<MTOK, 256, 0, stream>>>(out, ln2, tok);

  // up = y @ wu^T (bf16) — 256^2 8-phase kernel (512 blocks)
  gemm256<0><<<dim3(DFFN / 256, MTOK / 256), 512, 0, stream>>>(
      tok, wu_b, upb, nullptr, MTOK, DFFN, DMODEL, DMODEL);

  // gate halves: silu(y @ wg^T) f32 (256 blocks each) -> topk into upb
  for (int half = 0; half < 2; ++half) {
    const u16* yh = tok + (size_t)half * (MTOK / 2) * DMODEL;
    u16* uph = upb + (size_t)half * (MTOK / 2) * DFFN;
    gemm256<3><<<dim3(DFFN / 256, (MTOK / 2) / 256), 512, 0, stream>>>(
        yh, wg_b, gateh, nullptr, MTOK / 2, DFFN, DMODEL, DMODEL);
    topk_kernel<<<MTOK / 2, 256, 0, stream>>>(gateh, uph);
  }

  // wd -> bf16 (into S low half; gate halves dead, wg_b dead -> p0)
  cvt(wd, wd_b, (size_t)DMODEL * DFFN);

  // down: split-K x2 over the 8-phase 256^2 kernel (256 blocks = full chip)
  gemm256<4><<<dim3(DMODEL / 256, MTOK / 256, 2), 512, 0, stream>>>(
      upb, wd_b, p0, p1, MTOK, DMODEL, DFFN / 2, DFFN);

  // out = h + p0 + p1
  redadd_kernel<<<(MTOK * DMODEL) / 1024, 256, 0, stream>>>(out, p0, p1);
}

// Round 12
// 967.213 us; speedup vs baseline: 1.3240x; 1.0870x over previous
//
#include <hip/hip_runtime.h>
#include <stdint.h>

constexpr int SEQ    = 2048;
constexpr int DMODEL = 2048;
constexpr int NHEADS = 16;
constexpr int NKVH   = 4;
constexpr int HDIM   = 128;
constexpr int DFFN   = 8192;
constexpr int BATCH  = 2;
constexpr int MTOK   = BATCH * SEQ;   // 4096 tokens
constexpr int KKEEP  = DFFN / 2;      // 4096

typedef __bf16 bf16x8 __attribute__((ext_vector_type(8)));
typedef float  f32x4  __attribute__((ext_vector_type(4)));
typedef float  f32x16 __attribute__((ext_vector_type(16)));
typedef unsigned short u16;
typedef unsigned int   u32;

__device__ __forceinline__ u16 f2bu(float f) {  // f32 -> bf16 bits, RNE
  u32 x = __builtin_bit_cast(u32, f);
  return (u16)((x + 0x7FFFu + ((x >> 16) & 1u)) >> 16);
}
__device__ __forceinline__ float b2f(u16 u) {
  u32 v = ((u32)u) << 16;
  return __builtin_bit_cast(float, v);
}
__device__ __forceinline__ void gl_lds16(const void* g, void* l) {
  // 16B per lane; LDS dest = wave-uniform base + lane*16
  __builtin_amdgcn_global_load_lds((const __attribute__((address_space(1))) u32*)g,
                                   (__attribute__((address_space(3))) u32*)l, 16, 0, 0);
}

// ---------------- weight convert f32 -> bf16 ----------------
__global__ __launch_bounds__(256) void cvt_kernel(const float* __restrict__ in,
                                                  u16* __restrict__ out, int n) {
  int i = (blockIdx.x * 256 + threadIdx.x) * 4;
  if (i >= n) return;
  float4 v = *(const float4*)(in + i);
  uint2 pk;
  pk.x = (u32)f2bu(v.x) | ((u32)f2bu(v.y) << 16);
  pk.y = (u32)f2bu(v.z) | ((u32)f2bu(v.w) << 16);
  *(uint2*)(out + i) = pk;
}

// ---------------- reduce: out += p0 + p1 (split-K epilogue) ----------------
__global__ __launch_bounds__(256) void redadd_kernel(float* __restrict__ out,
                                                     const float* __restrict__ p0,
                                                     const float* __restrict__ p1) {
  int i = (blockIdx.x * 256 + threadIdx.x) * 4;
  float4 o = *(const float4*)(out + i);
  float4 a = *(const float4*)(p0 + i);
  float4 b = *(const float4*)(p1 + i);
  o.x += a.x + b.x; o.y += a.y + b.y; o.z += a.z + b.z; o.w += a.w + b.w;
  *(float4*)(out + i) = o;
}

// ---------------- RMSNorm: f32 row -> bf16 row ----------------
__global__ __launch_bounds__(256) void rmsnorm_kernel(const float* __restrict__ in,
                                                      const float* __restrict__ w,
                                                      u16* __restrict__ out) {
  const int tid = threadIdx.x;
  const size_t row = blockIdx.x;
  const float* x = in + row * DMODEL;
  float4 v0 = *(const float4*)(x + tid * 4);
  float4 v1 = *(const float4*)(x + 1024 + tid * 4);
  float s = v0.x*v0.x + v0.y*v0.y + v0.z*v0.z + v0.w*v0.w
          + v1.x*v1.x + v1.y*v1.y + v1.z*v1.z + v1.w*v1.w;
#pragma unroll
  for (int off = 1; off < 64; off <<= 1) s += __shfl_xor(s, off, 64);
  __shared__ float wsum[4];
  if ((tid & 63) == 0) wsum[tid >> 6] = s;
  __syncthreads();
  s = wsum[0] + wsum[1] + wsum[2] + wsum[3];
  const float rinv = rsqrtf(s * (1.0f / DMODEL) + 1e-6f);
  u16* o = out + row * DMODEL;
#pragma unroll
  for (int part = 0; part < 2; ++part) {
    int c = part * 1024 + tid * 4;
    float4 vv = (part == 0) ? v0 : v1;
    float4 wv = *(const float4*)(w + c);
    uint2 pk;
    pk.x = (u32)f2bu(vv.x * rinv * wv.x) | ((u32)f2bu(vv.y * rinv * wv.y) << 16);
    pk.y = (u32)f2bu(vv.z * rinv * wv.z) | ((u32)f2bu(vv.w * rinv * wv.w) << 16);
    *(uint2*)(o + c) = pk;
  }
}

// ---------------- 128x128 GEMM (min-2-phase), C = A @ B^T ------------------
// EPI: 0 = bf16 store, 1 = transposed V store, 2 = f32 + residual (res may
//      alias C), 3 = f32 silu
template <int EPI>
__global__ __launch_bounds__(256, 2)
void gemm_bt(const u16* __restrict__ A, const u16* __restrict__ B,
             void* __restrict__ C, const float* res,
             int M, int N, int K) {
  __shared__ u16 As[2][128 * 64];
  __shared__ u16 Bs[2][128 * 64];
  const int tid = threadIdx.x;
  const int wave = tid >> 6, lane = tid & 63;
  const int nwg = gridDim.x * gridDim.y;
  const int lin = blockIdx.y * gridDim.x + blockIdx.x;
  const int swz = (lin & 7) * (nwg >> 3) + (lin >> 3);
  const int m0 = (swz / gridDim.x) * 128, n0 = (swz % gridDim.x) * 128;
  const int r_in = lane >> 3, chk = lane & 7;   // staging: 8 rows x 8 chunks / KB
  const int fk = lane >> 4, fc = lane & 15;     // MFMA fragment indices
  const int wm = (wave >> 1) * 64, wn = (wave & 1) * 64;
  const int nt = K >> 6;
  f32x4 acc[4][4] = {};

  auto stage = [&](int buf, int t) {
    const int kt = t * 64;
#pragma unroll
    for (int i = 0; i < 4; ++i) {
      int row = wave * 32 + i * 8 + r_in;
      int gc = chk ^ (row & 7);   // pre-swizzled source, linear LDS dest
      gl_lds16(A + (size_t)(m0 + row) * K + kt + gc * 8, &As[buf][(wave * 32 + i * 8) * 64]);
    }
#pragma unroll
    for (int i = 0; i < 4; ++i) {
      int row = wave * 32 + i * 8 + r_in;
      int gc = chk ^ (row & 7);
      gl_lds16(B + (size_t)(n0 + row) * K + kt + gc * 8, &Bs[buf][(wave * 32 + i * 8) * 64]);
    }
  };

  stage(0, 0);
  asm volatile("s_waitcnt vmcnt(0)" ::: "memory");
  __builtin_amdgcn_s_barrier();

  for (int t = 0; t < nt; ++t) {
    if (t + 1 < nt) stage((t + 1) & 1, t + 1);   // issue-early: overlaps MFMA below
    const u16* Ab = As[t & 1];
    const u16* Bb = Bs[t & 1];
#pragma unroll
    for (int kk = 0; kk < 2; ++kk) {
      bf16x8 a[4], b[4];
#pragma unroll
      for (int i = 0; i < 4; ++i) {
        int row = wm + i * 16 + fc;
        int c = (kk * 4 + fk) ^ (row & 7);
        a[i] = *(const bf16x8*)(Ab + row * 64 + c * 8);
      }
#pragma unroll
      for (int j = 0; j < 4; ++j) {
        int row = wn + j * 16 + fc;
        int c = (kk * 4 + fk) ^ (row & 7);
        b[j] = *(const bf16x8*)(Bb + row * 64 + c * 8);
      }
#pragma unroll
      for (int i = 0; i < 4; ++i)
#pragma unroll
        for (int j = 0; j < 4; ++j)
          acc[i][j] = __builtin_amdgcn_mfma_f32_16x16x32_bf16(a[i], b[j], acc[i][j], 0, 0, 0);
    }
    asm volatile("s_waitcnt vmcnt(0)" ::: "memory");  // staged loads landed (late drain)
    __builtin_amdgcn_s_barrier();
  }

  const int rb = fk * 4;  // C/D: col = lane&15, row = (lane>>4)*4 + reg
#pragma unroll
  for (int i = 0; i < 4; ++i) {
#pragma unroll
    for (int j = 0; j < 4; ++j) {
      int row = m0 + wm + i * 16 + rb;
      int col = n0 + wn + j * 16 + fc;
      f32x4 v = acc[i][j];
      if constexpr (EPI == 0) {
        u16* o = (u16*)C;
#pragma unroll
        for (int r = 0; r < 4; ++r) o[(size_t)(row + r) * N + col] = f2bu(v[r]);
      } else if constexpr (EPI == 1) {
        // vt[b][kvh][d][s] ; row = token (4 consecutive s), col = kvh*128+d
        u16* o = (u16*)C;
        int bb = row >> 11, s = row & (SEQ - 1);
        int kvh = col >> 7, d = col & (HDIM - 1);
        size_t base = (((size_t)bb * NKVH + kvh) * HDIM + d) * SEQ + s;
        uint2 pk;
        pk.x = (u32)f2bu(v[0]) | ((u32)f2bu(v[1]) << 16);
        pk.y = (u32)f2bu(v[2]) | ((u32)f2bu(v[3]) << 16);
        *(uint2*)(o + base) = pk;
      } else if constexpr (EPI == 2) {
        float* o = (float*)C;
#pragma unroll
        for (int r = 0; r < 4; ++r) {
          size_t idx = (size_t)(row + r) * N + col;
          float rv = res[idx];
          o[idx] = v[r] + rv;
        }
      } else {  // EPI == 3 : silu
        float* o = (float*)C;
#pragma unroll
        for (int r = 0; r < 4; ++r) {
          float g = v[r];
          o[(size_t)(row + r) * N + col] = g / (1.0f + __expf(-g));
        }
      }
    }
  }
}

// ---------------- 256x256 GEMM, 8-phase counted-vmcnt, ring-3 A ------------
// Proven r8 skeleton (phase composition 12/4/4/4 ds_reads, midbar/endbar,
// MFMA order) UNCHANGED. Only the stage->slot mapping + A triple-buffer:
// As[3][2][...] (tile t in As[t%3]) frees As[(u+2)%3] at prev-iter ph8, so
// A halves stage at ph1/ph2 -> 6-7 phases of flight (was 2-3). Slots:
//  ph1: A0(u+2)  ph2: A1(u+2)  ph3: B0(u+2)  ph4: B1(u+2)  W4
//  ph5: A0(v+2)  ph6: A1(v+2)  ph7: B0(v+2)  ph8: B1(v+2)  W8
// Steady state: 16 outstanding at each wait, retire 8 -> vmcnt(8).
// W4 retires {A(v),B(v)} (needed ph5); W8 retires {A(u+2),B(u+2)} (needed
// next ph1). Prologue: B(0),A(0),A(1),B(1) + vmcnt(8) (retires tile 0).
// Last iter: W4 -> vmcnt(0), W8 -> skip. WAR: each stage's buffer readers
// drained >=1 barrier before the stage issues. LDS = 96 + 64 = 160 KiB.
template <int EPI>
__global__ __launch_bounds__(512, 2)
void gemm256(const u16* __restrict__ A, const u16* __restrict__ B,
             void* __restrict__ C, void* __restrict__ C2,
             int M, int N, int K, int lda) {
  __shared__ u16 As[3][2][128 * 64];
  __shared__ u16 Bs[2][2][128 * 64];
  const int tid = threadIdx.x;
  const int wave = tid >> 6, lane = tid & 63;
  const int nwg = gridDim.x * gridDim.y;
  const int lin = blockIdx.y * gridDim.x + blockIdx.x;
  const int swz = (lin & 7) * (nwg >> 3) + (lin >> 3);
  const int m0 = (swz / gridDim.x) * 256, n0 = (swz % gridDim.x) * 256;
  const int kh = blockIdx.z;
  A += (size_t)kh * K;
  B += (size_t)kh * K;
  const int wm = wave >> 2, wn = wave & 3;
  const int fk = lane >> 4, fc = lane & 15;
  const int nt = K >> 6, ni = nt >> 1;
  const int s_sub = lane >> 3;
  const int s_gc  = (lane & 7) ^ s_sub;   // pre-swizzled source chunk
  f32x4 acc[8][4] = {};
  bf16x8 b0[4], b1[4], a[4];

  auto sA = [&](int buf, int h, int t) {   // stage one A half-tile (2 loads)
    const u16* src = A + (size_t)(m0 + h * 128) * lda + t * 64;
    u16* dst = &As[buf][h][0];
#pragma unroll
    for (int I = 0; I < 2; ++I) {
      int row = I * 64 + wave * 8 + s_sub;
      gl_lds16(src + (size_t)row * lda + s_gc * 8, dst + (I * 512 + wave * 64) * 8);
    }
  };
  auto sB = [&](int buf, int h, int t) {
    const u16* src = B + (size_t)(n0 + h * 128) * lda + t * 64;
    u16* dst = &Bs[buf][h][0];
#pragma unroll
    for (int I = 0; I < 2; ++I) {
      int row = I * 64 + wave * 8 + s_sub;
      gl_lds16(src + (size_t)row * lda + s_gc * 8, dst + (I * 512 + wave * 64) * 8);
    }
  };
  auto rb = [&](const u16* Bh) {   // all 8 b-fragments of this K-tile
#pragma unroll
    for (int n = 0; n < 4; ++n) {
      int row = (wn & 1) * 64 + n * 16 + fc;
      b0[n] = *(const bf16x8*)(Bh + row * 64 + ((fk) ^ (row & 7)) * 8);
      b1[n] = *(const bf16x8*)(Bh + row * 64 + ((4 + fk) ^ (row & 7)) * 8);
    }
  };
  auto ra = [&](const u16* Ah, int mh, int kk) {
#pragma unroll
    for (int m = 0; m < 4; ++m) {
      int row = mh * 64 + m * 16 + fc;
      a[m] = *(const bf16x8*)(Ah + row * 64 + ((kk * 4 + fk) ^ (row & 7)) * 8);
    }
  };
  auto midbar = [&]() {
    __builtin_amdgcn_s_barrier();
    asm volatile("s_waitcnt lgkmcnt(0)" ::: "memory");
    __builtin_amdgcn_sched_barrier(0);
    __builtin_amdgcn_s_setprio(1);
  };
  auto endbar = [&]() {
    __builtin_amdgcn_s_setprio(0);
    __builtin_amdgcn_s_barrier();
  };
  auto mfma16 = [&](int mh, bf16x8* bb) {
#pragma unroll
    for (int m = 0; m < 4; ++m)
#pragma unroll
      for (int n = 0; n < 4; ++n)
        acc[mh * 4 + m][n] =
            __builtin_amdgcn_mfma_f32_16x16x32_bf16(a[m], bb[n], acc[mh * 4 + m][n], 0, 0, 0);
  };

  // prologue: B(0), A(0), A(1), B(1); vmcnt(8) retires tile 0 (oldest 8)
  sB(0, 0, 0); sB(0, 1, 0);
  sA(0, 0, 0); sA(0, 1, 0);
  sA(1, 0, 1); sA(1, 1, 1);
  sB(1, 0, 1); sB(1, 1, 1);
  asm volatile("s_waitcnt vmcnt(8)" ::: "memory");
  __builtin_amdgcn_s_barrier();

  int a0 = 0, a1 = 1;   // As ring indices: tile u -> As[a0], tile v -> As[a1]
  for (int i = 0; i < ni; ++i) {
    const int u = 2 * i, v = 2 * i + 1;
    const bool more = (i + 1 < ni);
    const int aU2 = (a0 + 2) % 3;   // buffer for tile u+2 (held u-1, free)
    const int aV2 = (a1 + 2) % 3;   // buffer for tile v+2 (held u, free ph5)
    const u16* Au = &As[a0][wm][0];
    const u16* Bu = &Bs[0][wn >> 1][0];
    const u16* Av = &As[a1][wm][0];
    const u16* Bv = &Bs[1][wn >> 1][0];
    // ---- u window ----
    rb(Bu); ra(Au, 0, 0); if (more) sA(aU2, 0, u + 2);   // ph1: 12 reads
    midbar(); mfma16(0, b0); endbar();
    ra(Au, 1, 0); if (more) sA(aU2, 1, u + 2);           // ph2
    midbar(); mfma16(1, b0); endbar();
    ra(Au, 0, 1); if (more) sB(0, 0, u + 2);             // ph3
    midbar(); mfma16(0, b1); endbar();
    ra(Au, 1, 1); if (more) sB(0, 1, u + 2);             // ph4
    midbar(); mfma16(1, b1);
    __builtin_amdgcn_s_setprio(0);
    if (more) asm volatile("s_waitcnt vmcnt(8)" ::: "memory");
    else      asm volatile("s_waitcnt vmcnt(0)" ::: "memory");
    __builtin_amdgcn_s_barrier();
    // ---- v window ----
    rb(Bv); ra(Av, 0, 0); if (more) sA(aV2, 0, v + 2);   // ph5
    midbar(); mfma16(0, b0); endbar();
    ra(Av, 1, 0); if (more) sA(aV2, 1, v + 2);           // ph6
    midbar(); mfma16(1, b0); endbar();
    ra(Av, 0, 1); if (more) sB(1, 0, v + 2);             // ph7
    midbar(); mfma16(0, b1); endbar();
    ra(Av, 1, 1); if (more) sB(1, 1, v + 2);             // ph8
    midbar(); mfma16(1, b1);
    __builtin_amdgcn_s_setprio(0);
    if (more) {
      asm volatile("s_waitcnt vmcnt(8)" ::: "memory");
    }
    __builtin_amdgcn_s_barrier();
    a0 = aU2; a1 = aV2;
  }

  const int rbase = fk * 4;  // C/D: col = lane&15, row = (lane>>4)*4 + reg
#pragma unroll
  for (int m = 0; m < 8; ++m) {
#pragma unroll
    for (int n = 0; n < 4; ++n) {
      int row = m0 + wm * 128 + m * 16 + rbase;
      int col = n0 + wn * 64 + n * 16 + fc;
      f32x4 vv = acc[m][n];
      if constexpr (EPI == 0) {
        u16* o = (u16*)C;
#pragma unroll
        for (int r = 0; r < 4; ++r) o[(size_t)(row + r) * N + col] = f2bu(vv[r]);
      } else if constexpr (EPI == 3) {  // f32 silu
        float* o = (float*)C;
#pragma unroll
        for (int r = 0; r < 4; ++r) {
          float g = vv[r];
          o[(size_t)(row + r) * N + col] = g / (1.0f + __expf(-g));
        }
      } else {  // EPI == 4 : f32 partial store (split-K)
        float* o = (kh == 0) ? (float*)C : (float*)C2;
#pragma unroll
        for (int r = 0; r < 4; ++r) o[(size_t)(row + r) * N + col] = vv[r];
      }
    }
  }
}

// ---------------- flash attention (causal GQA, swapped-QK, 32x32 MFMA) -----
__global__ __launch_bounds__(256, 2)
void attn_kernel(const u16* __restrict__ Q, const u16* __restrict__ Kb,
                 const u16* __restrict__ Vt, u16* __restrict__ O) {
  __shared__ u16 Ksh[2 * 32 * 128];   // [buf][kv][d], chunk^(kv&15) swizzle
  __shared__ u16 Vsh[2 * 128 * 32];   // [buf][d][kv], chunk^((d>>1)&3) swizzle
  const int tid = threadIdx.x, wave = tid >> 6, lane = tid & 63;
  const int half = lane >> 5, l31 = lane & 31;
  // Remap: d and d+256 share (b,h) with complementary bx (pair work = 72
  // tiles, balances causal tail); d&7 pins one (b,kvh) per XCD for L2.
  const int d_lin = blockIdx.x + gridDim.x * (blockIdx.y + gridDim.y * blockIdx.z);
  const int x = d_lin & 255, hi = d_lin >> 8;
  const int e = (x & 7) * 32 + (x >> 3);
  const int q = e & 7, h = (e >> 3) & 15, b = e >> 7;
  const int bx = hi ? 15 - q : q;
  const int kvh = h >> 2;
  const int qw = bx * 128 + wave * 32;
  const float SC = 0.08838834764831845f;  // 1/sqrt(128)
  const int ntb = bx * 4 + 4;             // staged tiles per block
  const int nmy = bx * 4 + wave;          // last tile index this wave computes

  bf16x8 qf[8];
  {
    const u16* qp = Q + ((size_t)(b * SEQ + qw + l31)) * DMODEL + h * HDIM + half * 8;
#pragma unroll
    for (int s = 0; s < 8; ++s) qf[s] = *(const bf16x8*)(qp + s * 16);
  }
  f32x16 oacc[4] = {};
  float m_run = -1e30f, l_run = 0.0f;
  const size_t vbase = ((size_t)(b * NKVH + kvh)) * HDIM * SEQ;
  const u16* kbase = Kb + (size_t)b * SEQ * (NKVH * HDIM) + kvh * HDIM;

  auto stage = [&](int bi, int k0) {
    u16* Kd = Ksh + bi * 4096;
    u16* Vd = Vsh + bi * 4096;
#pragma unroll
    for (int ii = 0; ii < 2; ++ii) {
      int inst = wave * 2 + ii;
      {
        int row = inst * 4 + (lane >> 4);
        int c = (lane & 15) ^ (row & 15);
        gl_lds16(kbase + (size_t)(k0 + row) * (NKVH * HDIM) + c * 8, Kd + inst * 512);
      }
      {
        int row = inst * 16 + (lane >> 2);
        int c = (lane & 3) ^ ((row >> 1) & 3);
        gl_lds16(Vt + vbase + (size_t)row * SEQ + k0 + c * 8, Vd + inst * 512);
      }
    }
  };

  stage(0, 0);
  __syncthreads();

  for (int t = 0; t < ntb; ++t) {
    if (t + 1 < ntb) stage((t + 1) & 1, (t + 1) * 32);
    if (t <= nmy) {
      const u16* Kd = Ksh + (t & 1) * 4096;
      const u16* Vd = Vsh + (t & 1) * 4096;
      f32x16 st = {};
#pragma unroll
      for (int s = 0; s < 8; ++s) {
        int c = (half + 2 * s) ^ (l31 & 15);
        bf16x8 kf = *(const bf16x8*)(Kd + l31 * 128 + c * 8);
        st = __builtin_amdgcn_mfma_f32_32x32x16_bf16(kf, qf[s], st, 0, 0, 0);
      }
      const bool diag = (t * 32 == qw);
      float sv[16];
#pragma unroll
      for (int r = 0; r < 16; ++r) {
        float xx = st[r] * SC;
        if (diag) {
          int kvl = (r & 3) + 8 * (r >> 2) + 4 * half;
          if (kvl > l31) xx = -1e30f;
        }
        sv[r] = xx;
      }
      float mx = sv[0];
#pragma unroll
      for (int r = 1; r < 16; ++r) mx = fmaxf(mx, sv[r]);
      mx = fmaxf(mx, __shfl_xor(mx, 32, 64));
      if (__any(mx > m_run + 4.0f)) {   // defer-max (exact): rescale rarely
        float mnew = fmaxf(m_run, mx);
        float alpha = __expf(m_run - mnew);
        m_run = mnew;
        l_run *= alpha;
#pragma unroll
        for (int r = 0; r < 16; ++r) {
          float ar = __shfl(alpha, (r & 3) + 8 * (r >> 2) + 4 * half, 64);
#pragma unroll
          for (int dt = 0; dt < 4; ++dt) oacc[dt][r] *= ar;
        }
      }
      float p[16];
      float rs = 0.0f;
#pragma unroll
      for (int r = 0; r < 16; ++r) { p[r] = __expf(sv[r] - m_run); rs += p[r]; }
      rs += __shfl_xor(rs, 32, 64);
      l_run += rs;
      u32 c01 = (u32)f2bu(p[0])  | ((u32)f2bu(p[1])  << 16);
      u32 c23 = (u32)f2bu(p[2])  | ((u32)f2bu(p[3])  << 16);
      u32 c45 = (u32)f2bu(p[4])  | ((u32)f2bu(p[5])  << 16);
      u32 c67 = (u32)f2bu(p[6])  | ((u32)f2bu(p[7])  << 16);
      u32 c89 = (u32)f2bu(p[8])  | ((u32)f2bu(p[9])  << 16);
      u32 cAB = (u32)f2bu(p[10]) | ((u32)f2bu(p[11]) << 16);
      u32 cCD = (u32)f2bu(p[12]) | ((u32)f2bu(p[13]) << 16);
      u32 cEF = (u32)f2bu(p[14]) | ((u32)f2bu(p[15]) << 16);
      u32 paw[2][4];
      {
        u32 sA = __shfl_xor(c01, 32, 64), sB = __shfl_xor(c23, 32, 64);
        u32 sC = __shfl_xor(c45, 32, 64), sD = __shfl_xor(c67, 32, 64);
        paw[0][0] = half ? sC : c01;  paw[0][1] = half ? sD : c23;
        paw[0][2] = half ? c45 : sA;  paw[0][3] = half ? c67 : sB;
      }
      {
        u32 sA = __shfl_xor(c89, 32, 64), sB = __shfl_xor(cAB, 32, 64);
        u32 sC = __shfl_xor(cCD, 32, 64), sD = __shfl_xor(cEF, 32, 64);
        paw[1][0] = half ? sC : c89;  paw[1][1] = half ? sD : cAB;
        paw[1][2] = half ? cCD : sA;  paw[1][3] = half ? cEF : sB;
      }
#pragma unroll
      for (int ks = 0; ks < 2; ++ks) {
        bf16x8 paf = __builtin_bit_cast(bf16x8, *(uint4*)&paw[ks][0]);
#pragma unroll
        for (int dt = 0; dt < 4; ++dt) {
          int row = dt * 32 + l31;
          int c = (half + 2 * ks) ^ ((row >> 1) & 3);
          bf16x8 vf = *(const bf16x8*)(Vd + row * 32 + c * 8);
          oacc[dt] = __builtin_amdgcn_mfma_f32_32x32x16_bf16(paf, vf, oacc[dt], 0, 0, 0);
        }
      }
    }
    __syncthreads();
  }

  float rinv = 1.0f / l_run;
  u16* ob = O + ((size_t)(b * SEQ + qw)) * DMODEL + h * HDIM + l31;
#pragma unroll
  for (int r = 0; r < 16; ++r) {
    int qr = (r & 3) + 8 * (r >> 2) + 4 * half;
    float ir = __shfl(rinv, qr, 64);
#pragma unroll
    for (int dt = 0; dt < 4; ++dt)
      ob[(size_t)qr * DMODEL + dt * 32] = f2bu(oacc[dt][r] * ir);
  }
}

// ---------------- top-k (exact radix select) + gate*up, in-place over up ---
__global__ __launch_bounds__(256)
void topk_kernel(const float* __restrict__ gate, u16* __restrict__ upact) {
  __shared__ u32 sabs[DFFN];       // silu(gate) f32 bits
  __shared__ u32 hist[4][256];
  __shared__ u32 ss[257];
  __shared__ u32 sh_prefix, sh_rem;
  const int tid = threadIdx.x, wave = tid >> 6;
  const size_t row = blockIdx.x;
  const float* g = gate + row * DFFN;
  for (int it = 0; it < 4; ++it) {
    int e = it * 2048 + tid * 8;
    float4 a = *(const float4*)(g + e);
    float4 b = *(const float4*)(g + e + 4);
    sabs[e + 0] = __builtin_bit_cast(u32, a.x);
    sabs[e + 1] = __builtin_bit_cast(u32, a.y);
    sabs[e + 2] = __builtin_bit_cast(u32, a.z);
    sabs[e + 3] = __builtin_bit_cast(u32, a.w);
    sabs[e + 4] = __builtin_bit_cast(u32, b.x);
    sabs[e + 5] = __builtin_bit_cast(u32, b.y);
    sabs[e + 6] = __builtin_bit_cast(u32, b.z);
    sabs[e + 7] = __builtin_bit_cast(u32, b.w);
  }
  if (tid == 0) { sh_prefix = 0; sh_rem = KKEEP; }
  __syncthreads();
  for (int pass = 0; pass < 4; ++pass) {
    const int p = 24 - pass * 8;
    const u32 mask_hi = (pass == 0) ? 0u : (0xFFFFFFFFu << (p + 8));
    for (int i = tid; i < 1024; i += 256) ((u32*)hist)[i] = 0;
    __syncthreads();
    const u32 prefix = sh_prefix, rem = sh_rem;
    for (int it = 0; it < 4; ++it) {
      int e = it * 2048 + tid * 8;
#pragma unroll
      for (int j = 0; j < 8; ++j) {
        u32 mg = sabs[e + j] & 0x7FFFFFFFu;
        if ((mg & mask_hi) == (prefix & mask_hi))
          atomicAdd(&hist[wave][(mg >> p) & 0xFF], 1u);
      }
    }
    __syncthreads();
    ss[tid] = hist[0][tid] + hist[1][tid] + hist[2][tid] + hist[3][tid];
    if (tid == 0) ss[256] = 0;
    __syncthreads();
    for (int off = 1; off < 256; off <<= 1) {
      u32 v = (tid + off < 256) ? ss[tid + off] : 0u;
      __syncthreads();
      ss[tid] += v;
      __syncthreads();
    }
    if (ss[tid] >= rem && ss[tid + 1] < rem) {
      sh_prefix = prefix | ((u32)tid << p);
      sh_rem = rem - ss[tid + 1];
    }
    __syncthreads();
  }
  const u32 thr = sh_prefix;
  u16* ua = upact + row * DFFN;
  for (int it = 0; it < 4; ++it) {
    int e = it * 2048 + tid * 8;
    uint4 uv = *(const uint4*)(ua + e);
    const u16* up16 = (const u16*)&uv;
    u16 outp[8];
#pragma unroll
    for (int j = 0; j < 8; ++j) {
      u32 bits = sabs[e + j];
      u32 mg = bits & 0x7FFFFFFFu;
      float gg = __builtin_bit_cast(float, bits);
      float prod = (mg >= thr) ? gg * b2f(up16[j]) : 0.0f;
      outp[j] = f2bu(prod);
    }
    uint4 ov;
    ov.x = (u32)outp[0] | ((u32)outp[1] << 16);
    ov.y = (u32)outp[2] | ((u32)outp[3] << 16);
    ov.z = (u32)outp[4] | ((u32)outp[5] << 16);
    ov.w = (u32)outp[6] | ((u32)outp[7] << 16);
    *(uint4*)(ua + e) = ov;
  }
}

// ---------------- launcher ----------------
extern "C" void kernel_launch(void* const* d_in, const int* in_sizes, int n_in,
                              void* d_out, int out_size, void* d_ws, size_t ws_size,
                              hipStream_t stream) {
  const float* hidden = (const float*)d_in[0];
  const float* wq = (const float*)d_in[1];
  const float* wk = (const float*)d_in[2];
  const float* wv = (const float*)d_in[3];
  const float* wo = (const float*)d_in[4];
  const float* ln1 = (const float*)d_in[5];
  const float* ln2 = (const float*)d_in[6];
  const float* wg = (const float*)d_in[7];
  const float* wu = (const float*)d_in[8];
  const float* wd = (const float*)d_in[9];
  float* out = (float*)d_out;
  (void)in_sizes; (void)n_in; (void)out_size;

  // ---- workspace layout (lifetime-aliased, ~196 MB total) ----
  size_t off = 0;
  auto alloc = [&](size_t n) { char* r = (char*)d_ws + off; off += (n + 255) & ~(size_t)255; return r; };
  u16* wq_b = (u16*)alloc((size_t)DMODEL * DMODEL * 2);      // 8 MB
  u16* wk_b = (u16*)alloc((size_t)NKVH * HDIM * DMODEL * 2); // 2 MB
  u16* wv_b = (u16*)alloc((size_t)NKVH * HDIM * DMODEL * 2); // 2 MB
  u16* wo_b = (u16*)alloc((size_t)DMODEL * DMODEL * 2);      // 8 MB
  u16* wg_b = (u16*)alloc((size_t)DFFN * DMODEL * 2);        // 32 MB
  u16* tok  = (u16*)alloc((size_t)MTOK * DMODEL * 2);        // 16 MB: x -> o -> y
  u16* upb  = (u16*)alloc((size_t)MTOK * DFFN * 2);          // 64 MB
  char* S   = alloc((size_t)(MTOK / 2) * DFFN * 4);          // 64 MB shared region
  // S phase 1: qb(16) kb(4) vtb(4) wu_b(32)
  u16* qb   = (u16*)S;
  u16* kb   = (u16*)(S + (size_t)MTOK * DMODEL * 2);
  u16* vtb  = (u16*)(S + (size_t)MTOK * DMODEL * 2 + (size_t)MTOK * NKVH * HDIM * 2);
  u16* wu_b = (u16*)(S + (size_t)MTOK * DMODEL * 2 + 2 * (size_t)MTOK * NKVH * HDIM * 2);
  // S phase 2: gate half (f32, 2048 x 8192)
  float* gateh = (float*)S;
  // S phase 3: wd_b (32 MB) + split-K partial p1 (32 MB); p0 reuses wg_b slot
  u16* wd_b = (u16*)S;
  float* p1 = (float*)(S + (size_t)32 * 1024 * 1024);
  float* p0 = (float*)wg_b;   // wg_b dead after gate GEMMs
  const size_t needed = off;
  if (ws_size < needed) return;  // clean fast-fail (diagnostic) instead of OOB hang

  auto cvt = [&](const float* src, u16* dst, size_t n) {
    cvt_kernel<<<dim3((unsigned)(n / 1024)), 256, 0, stream>>>(src, dst, (int)n);
  };
  cvt(wq, wq_b, (size_t)DMODEL * DMODEL);
  cvt(wk, wk_b, (size_t)NKVH * HDIM * DMODEL);
  cvt(wv, wv_b, (size_t)NKVH * HDIM * DMODEL);
  cvt(wo, wo_b, (size_t)DMODEL * DMODEL);
  cvt(wg, wg_b, (size_t)DFFN * DMODEL);
  cvt(wu, wu_b, (size_t)DFFN * DMODEL);

  // x = rmsnorm(hidden, ln1)
  rmsnorm_kernel<<<MTOK, 256, 0, stream>>>(hidden, ln1, tok);

  gemm_bt<0><<<dim3(DMODEL / 128, MTOK / 128), 256, 0, stream>>>(
      tok, wq_b, qb, nullptr, MTOK, DMODEL, DMODEL);
  gemm_bt<0><<<dim3(NKVH * HDIM / 128, MTOK / 128), 256, 0, stream>>>(
      tok, wk_b, kb, nullptr, MTOK, NKVH * HDIM, DMODEL);
  gemm_bt<1><<<dim3(NKVH * HDIM / 128, MTOK / 128), 256, 0, stream>>>(
      tok, wv_b, vtb, nullptr, MTOK, NKVH * HDIM, DMODEL);

  // o -> tok (x dead)
  attn_kernel<<<dim3(SEQ / 128, NHEADS, BATCH), 256, 0, stream>>>(qb, kb, vtb, tok);

  // h = hidden + o @ wo^T   -> stored in d_out
  gemm_bt<2><<<dim3(DMODEL / 128, MTOK / 128), 256, 0, stream>>>(
      tok, wo_b, out, hidden, MTOK, DMODEL, DMODEL);

  // y = rmsnorm(h, ln2) -> tok (o dead)
  rmsnorm_kernel<<<MTOK, 256, 0, stream>>>(out, ln2, tok);

  // up = y @ wu^T (bf16) — 256^2 8-phase kernel (512 blocks)
  gemm256<0><<<dim3(DFFN / 256, MTOK / 256), 512, 0, stream>>>(
      tok, wu_b, upb, nullptr, MTOK, DFFN, DMODEL, DMODEL);

  // gate halves: silu(y @ wg^T) f32 (256 blocks each) -> topk into upb
  for (int half = 0; half < 2; ++half) {
    const u16* yh = tok + (size_t)half * (MTOK / 2) * DMODEL;
    u16* uph = upb + (size_t)half * (MTOK / 2) * DFFN;
    gemm256<3><<<dim3(DFFN / 256, (MTOK / 2) / 256), 512, 0, stream>>>(
        yh, wg_b, gateh, nullptr, MTOK / 2, DFFN, DMODEL, DMODEL);
    topk_kernel<<<MTOK / 2, 256, 0, stream>>>(gateh, uph);
  }

  // wd -> bf16 (into S low half; gate halves dead, wg_b dead -> p0)
  cvt(wd, wd_b, (size_t)DMODEL * DFFN);

  // down: split-K x2 over the 8-phase 256^2 kernel (256 blocks = full chip)
  gemm256<4><<<dim3(DMODEL / 256, MTOK / 256, 2), 512, 0, stream>>>(
      upb, wd_b, p0, p1, MTOK, DMODEL, DFFN / 2, DFFN);

  // out = h + p0 + p1
  redadd_kernel<<<(MTOK * DMODEL) / 1024, 256, 0, stream>>>(out, p0, p1);
}